// Round 1
// baseline (668.914 us; speedup 1.0000x reference)
//
#include <hip/hip_runtime.h>

#define HH 80
#define WW 80
#define HWN 6400
#define BN 16

static constexpr size_t BIGN = (size_t)BN * 64 * HWN;  // 6,553,600 floats

__device__ __forceinline__ float sigf(float v)  { return 1.f / (1.f + __expf(-v)); }
__device__ __forceinline__ float siluf(float v) { return v * sigf(v); }
__device__ __forceinline__ float tapf(const float* __restrict__ pl, int y, int x) {
  return ((unsigned)y < (unsigned)HH && (unsigned)x < (unsigned)WW) ? pl[y * WW + x] : 0.f;
}
// bn params stacked [g, b, m, v] each of length C
__device__ __forceinline__ float bnap(float v, const float* __restrict__ bn, int c, int C) {
  float s = bn[c] * rsqrtf(bn[3 * C + c] + 1e-5f);
  return v * s + (bn[C + c] - bn[2 * C + c] * s);
}

// ---------------- K1: 1x1 conv 256->128 + BN + SiLU, split hs/hb -------------
// grid (100, 2, 16), block 256
__global__ __launch_bounds__(256) void k_reduce(const float* __restrict__ x,
    const float* __restrict__ w, const float* __restrict__ bn,
    float* __restrict__ hs, float* __restrict__ hb) {
  __shared__ __align__(16) float Wt[1024];
  __shared__ __align__(16) float Xt[1024];
  const int t = threadIdx.x;
  const int p0 = blockIdx.x * 64, c0 = blockIdx.y * 64, b = blockIdx.z;
  const int tx = t & 15, ty = t >> 4;
  float acc[4][4] = {};
  const float* xb = x + (size_t)b * 256 * HWN;
  for (int k0 = 0; k0 < 256; k0 += 16) {
    __syncthreads();
    int idx = t;
#pragma unroll
    for (int r = 0; r < 4; ++r) {
      int c_l = idx >> 4, k_l = idx & 15;
      Wt[k_l * 64 + c_l] = w[(c0 + c_l) * 256 + k0 + k_l];
      idx += 256;
    }
    idx = t;
#pragma unroll
    for (int r = 0; r < 4; ++r) {
      int k_l = idx >> 6, p_l = idx & 63;
      Xt[k_l * 64 + p_l] = xb[(size_t)(k0 + k_l) * HWN + p0 + p_l];
      idx += 256;
    }
    __syncthreads();
#pragma unroll
    for (int kk = 0; kk < 16; ++kk) {
      const float4 wv = *reinterpret_cast<const float4*>(Wt + kk * 64 + ty * 4);
      const float4 xv = *reinterpret_cast<const float4*>(Xt + kk * 64 + tx * 4);
      const float wa[4] = {wv.x, wv.y, wv.z, wv.w};
      const float xa[4] = {xv.x, xv.y, xv.z, xv.w};
#pragma unroll
      for (int i = 0; i < 4; ++i)
#pragma unroll
        for (int j = 0; j < 4; ++j) acc[i][j] = fmaf(wa[i], xa[j], acc[i][j]);
    }
  }
  float* dstbase = (blockIdx.y == 0) ? hs : hb;
#pragma unroll
  for (int i = 0; i < 4; ++i) {
    int c = c0 + ty * 4 + i;
    float s = bn[c] * rsqrtf(bn[384 + c] + 1e-5f);
    float tt = bn[128 + c] - bn[256 + c] * s;
    float4 o;
    o.x = siluf(acc[i][0] * s + tt);
    o.y = siluf(acc[i][1] * s + tt);
    o.z = siluf(acc[i][2] * s + tt);
    o.w = siluf(acc[i][3] * s + tt);
    *reinterpret_cast<float4*>(dstbase + ((size_t)b * 64 + (c & 63)) * HWN + p0 + tx * 4) = o;
  }
}

// ---------------- K2: 3x3 offset conv (64->3) -> sample coords + mask --------
// grid (5, 5, 16), block 256 (16x16 tile)
__global__ __launch_bounds__(256) void k_offset(const float* __restrict__ hs,
    const float* __restrict__ w, const float* __restrict__ bias,
    float* __restrict__ sx, float* __restrict__ sy, float* __restrict__ msk) {
  __shared__ float tile[18 * 18];
  const int t = threadIdx.x;
  const int b = blockIdx.z;
  const int x0 = blockIdx.x * 16, y0 = blockIdx.y * 16;
  const int lx = t & 15, ly = t >> 4;
  float a0 = 0.f, a1 = 0.f, a2 = 0.f;
  for (int c = 0; c < 64; ++c) {
    __syncthreads();
    for (int i = t; i < 18 * 18; i += 256) {
      int tyy = i / 18, txx = i - tyy * 18;
      int gy = y0 + tyy - 1, gx = x0 + txx - 1;
      tile[i] = ((unsigned)gy < (unsigned)HH && (unsigned)gx < (unsigned)WW)
                    ? hs[((size_t)b * 64 + c) * HWN + gy * WW + gx] : 0.f;
    }
    __syncthreads();
    const float* wc = w + c * 9;  // w[ch][c][3][3], ch stride 576
#pragma unroll
    for (int dy = 0; dy < 3; ++dy)
#pragma unroll
      for (int dx = 0; dx < 3; ++dx) {
        float v = tile[(ly + dy) * 18 + lx + dx];
        a0 = fmaf(wc[dy * 3 + dx], v, a0);
        a1 = fmaf(wc[576 + dy * 3 + dx], v, a1);
        a2 = fmaf(wc[1152 + dy * 3 + dx], v, a2);
      }
  }
  a0 += bias[0];  // off_y
  a1 += bias[1];  // off_x
  a2 += bias[2];  // mask logit
  size_t o = (size_t)b * HWN + (y0 + ly) * WW + x0 + lx;
  const float sc = 79.f / 80.f;  // (grid+1)*0.5*(W-1) with off*(2/W) folds to p + off*(W-1)/W
  sx[o] = (float)(x0 + lx) + a1 * sc;
  sy[o] = (float)(y0 + ly) + a0 * sc;
  msk[o] = sigf(a2);
}

// ---------------- K3: bilinear grid sample * mask ----------------------------
// grid (25, 64, 16), block 256
__global__ __launch_bounds__(256) void k_gsample(const float* __restrict__ hs,
    const float* __restrict__ sx, const float* __restrict__ sy,
    const float* __restrict__ msk, float* __restrict__ xd) {
  const int p = blockIdx.x * 256 + threadIdx.x;
  const int c = blockIdx.y, b = blockIdx.z;
  const size_t bo = (size_t)b * HWN + p;
  float gx = sx[bo], gy = sy[bo], m = msk[bo];
  float x0f = floorf(gx), y0f = floorf(gy);
  float wx = gx - x0f, wy = gy - y0f;
  int ix0 = (int)x0f, iy0 = (int)y0f;
  int ix1 = ix0 + 1, iy1 = iy0 + 1;
  const float* pl = hs + ((size_t)b * 64 + c) * HWN;
  float v = 0.f;
  if ((unsigned)iy0 < (unsigned)HH && (unsigned)ix0 < (unsigned)WW) v = fmaf(pl[iy0 * WW + ix0], (1.f - wx) * (1.f - wy), v);
  if ((unsigned)iy0 < (unsigned)HH && (unsigned)ix1 < (unsigned)WW) v = fmaf(pl[iy0 * WW + ix1], wx * (1.f - wy), v);
  if ((unsigned)iy1 < (unsigned)HH && (unsigned)ix0 < (unsigned)WW) v = fmaf(pl[iy1 * WW + ix0], (1.f - wx) * wy, v);
  if ((unsigned)iy1 < (unsigned)HH && (unsigned)ix1 < (unsigned)WW) v = fmaf(pl[iy1 * WW + ix1], wx * wy, v);
  xd[((size_t)b * 64 + c) * HWN + p] = v * m;
}

// ---------------- K4: depthwise 3x3 (no act) ---------------------------------
// grid (25, 64, 16)
__global__ __launch_bounds__(256) void k_dw(const float* __restrict__ xd,
    const float* __restrict__ w, float* __restrict__ outp) {
  const int p = blockIdx.x * 256 + threadIdx.x;
  const int c = blockIdx.y, b = blockIdx.z;
  const int y = p / WW, x = p - y * WW;
  const float* pl = xd + ((size_t)b * 64 + c) * HWN;
  const float* wc = w + c * 9;
  float acc = 0.f;
#pragma unroll
  for (int dy = 0; dy < 3; ++dy)
#pragma unroll
    for (int dx = 0; dx < 3; ++dx)
      acc = fmaf(wc[dy * 3 + dx], tapf(pl, y + dy - 1, x + dx - 1), acc);
  outp[((size_t)b * 64 + c) * HWN + p] = acc;
}

// ---------------- K5: 1x1 conv 64->64 + BN + SiLU ----------------------------
// grid (100, 1, 16), block 256
__global__ __launch_bounds__(256) void k_pw(const float* __restrict__ in,
    const float* __restrict__ w, const float* __restrict__ bn, float* __restrict__ outp) {
  __shared__ __align__(16) float Wt[1024];
  __shared__ __align__(16) float Xt[1024];
  const int t = threadIdx.x;
  const int p0 = blockIdx.x * 64, b = blockIdx.z;
  const int tx = t & 15, ty = t >> 4;
  float acc[4][4] = {};
  for (int k0 = 0; k0 < 64; k0 += 16) {
    __syncthreads();
    int idx = t;
#pragma unroll
    for (int r = 0; r < 4; ++r) {
      int c_l = idx >> 4, k_l = idx & 15;
      Wt[k_l * 64 + c_l] = w[c_l * 64 + k0 + k_l];
      idx += 256;
    }
    idx = t;
#pragma unroll
    for (int r = 0; r < 4; ++r) {
      int k_l = idx >> 6, p_l = idx & 63;
      Xt[k_l * 64 + p_l] = in[((size_t)b * 64 + k0 + k_l) * HWN + p0 + p_l];
      idx += 256;
    }
    __syncthreads();
#pragma unroll
    for (int kk = 0; kk < 16; ++kk) {
      const float4 wv = *reinterpret_cast<const float4*>(Wt + kk * 64 + ty * 4);
      const float4 xv = *reinterpret_cast<const float4*>(Xt + kk * 64 + tx * 4);
      const float wa[4] = {wv.x, wv.y, wv.z, wv.w};
      const float xa[4] = {xv.x, xv.y, xv.z, xv.w};
#pragma unroll
      for (int i = 0; i < 4; ++i)
#pragma unroll
        for (int j = 0; j < 4; ++j) acc[i][j] = fmaf(wa[i], xa[j], acc[i][j]);
    }
  }
#pragma unroll
  for (int i = 0; i < 4; ++i) {
    int c = ty * 4 + i;
    float s = bn[c] * rsqrtf(bn[192 + c] + 1e-5f);
    float tt = bn[64 + c] - bn[128 + c] * s;
    float4 o;
    o.x = siluf(acc[i][0] * s + tt);
    o.y = siluf(acc[i][1] * s + tt);
    o.z = siluf(acc[i][2] * s + tt);
    o.w = siluf(acc[i][3] * s + tt);
    *reinterpret_cast<float4*>(outp + ((size_t)b * 64 + c) * HWN + p0 + tx * 4) = o;
  }
}

// ---------------- K6a: depthwise 1x7 + BN + SiLU -> a1 -----------------------
// grid (25, 64, 16)
__global__ __launch_bounds__(256) void k_a1(const float* __restrict__ hs,
    const float* __restrict__ w, const float* __restrict__ bn, float* __restrict__ a1) {
  const int p = blockIdx.x * 256 + threadIdx.x;
  const int c = blockIdx.y, b = blockIdx.z;
  const int y = p / WW, x = p - y * WW;
  const float* pl = hs + ((size_t)b * 64 + c) * HWN;
  const float* wc = w + c * 7;
  float acc = 0.f;
#pragma unroll
  for (int k = 0; k < 7; ++k) acc = fmaf(wc[k], tapf(pl, y, x + k - 3), acc);
  a1[((size_t)b * 64 + c) * HWN + p] = siluf(bnap(acc, bn, c, 64));
}

// ---------------- K6b: d2 + d3 + asym(7x1 of a1) -> ctx; star0 = BN(dcn*ctx) -
// grid (25, 64, 16)
__global__ __launch_bounds__(256) void k_ctxstar(const float* __restrict__ hs,
    const float* __restrict__ a1, const float* __restrict__ dcn,
    const float* __restrict__ wd2, const float* __restrict__ bnd2,
    const float* __restrict__ wd3, const float* __restrict__ bnd3,
    const float* __restrict__ wa2, const float* __restrict__ bna2,
    const float* __restrict__ cw, const float* __restrict__ bnstar,
    float* __restrict__ star0) {
  const int p = blockIdx.x * 256 + threadIdx.x;
  const int c = blockIdx.y, b = blockIdx.z;
  const int y = p / WW, x = p - y * WW;
  const float* pl = hs + ((size_t)b * 64 + c) * HWN;
  float d2 = 0.f, d3 = 0.f;
#pragma unroll
  for (int dy = 0; dy < 3; ++dy)
#pragma unroll
    for (int dx = 0; dx < 3; ++dx) {
      d2 = fmaf(wd2[c * 9 + dy * 3 + dx], tapf(pl, y + 2 * (dy - 1), x + 2 * (dx - 1)), d2);
      d3 = fmaf(wd3[c * 9 + dy * 3 + dx], tapf(pl, y + 3 * (dy - 1), x + 3 * (dx - 1)), d3);
    }
  const float* ap = a1 + ((size_t)b * 64 + c) * HWN;
  float as = 0.f;
#pragma unroll
  for (int k = 0; k < 7; ++k) as = fmaf(wa2[c * 7 + k], tapf(ap, y + k - 3, x), as);
  d2 = siluf(bnap(d2, bnd2, c, 64));
  d3 = siluf(bnap(d3, bnd3, c, 64));
  as = siluf(bnap(as, bna2, c, 64));
  float e0 = __expf(cw[0]), e1 = __expf(cw[1]), e2 = __expf(cw[2]);
  float inv = 1.f / (e0 + e1 + e2);
  float ctx = (e0 * d2 + e1 * d3 + e2 * as) * inv;
  float dv = dcn[((size_t)b * 64 + c) * HWN + p];
  star0[((size_t)b * 64 + c) * HWN + p] = bnap(dv * ctx, bnstar, c, 64);
}

// ---------------- K7: per-(b,c) spatial mean of star0 ------------------------
// grid (64, 16), block 256
__global__ __launch_bounds__(256) void k_cmean(const float* __restrict__ star0,
    float* __restrict__ mean) {
  const int c = blockIdx.x, b = blockIdx.y;
  const float* pl = star0 + ((size_t)b * 64 + c) * HWN;
  float s = 0.f;
  for (int i = threadIdx.x; i < HWN; i += 256) s += pl[i];
  __shared__ float red[256];
  red[threadIdx.x] = s;
  __syncthreads();
  for (int st = 128; st > 0; st >>= 1) {
    if (threadIdx.x < st) red[threadIdx.x] += red[threadIdx.x + st];
    __syncthreads();
  }
  if (threadIdx.x == 0) mean[b * 64 + c] = red[0] * (1.f / HWN);
}

// ---------------- K7b: ECA 1D conv (k=5, pad 2) + sigmoid --------------------
// grid (1), block 1024
__global__ __launch_bounds__(1024) void k_eca(const float* __restrict__ mean,
    const float* __restrict__ ew, float* __restrict__ ych) {
  const int t = threadIdx.x;  // t = b*64 + c
  const int c = t & 63;
  const int base = t - c;
  float acc = 0.f;
#pragma unroll
  for (int k = 0; k < 5; ++k) {
    int cc = c + k - 2;
    if ((unsigned)cc < 64u) acc = fmaf(ew[k], mean[base + cc], acc);
  }
  ych[t] = sigf(acc);
}

// ---------------- K8: star1 = star0*ych; channel mean/max --------------------
// grid (25, 16), block 256
__global__ __launch_bounds__(256) void k_spstats(const float* __restrict__ star0,
    const float* __restrict__ ych, float* __restrict__ star1,
    float* __restrict__ spmean, float* __restrict__ spmax) {
  const int p = blockIdx.x * 256 + threadIdx.x;
  const int b = blockIdx.y;
  float s = 0.f, mx = -1e30f;
  for (int c = 0; c < 64; ++c) {
    size_t o = ((size_t)b * 64 + c) * HWN + p;
    float v = star0[o] * ych[b * 64 + c];
    star1[o] = v;
    s += v;
    mx = fmaxf(mx, v);
  }
  spmean[(size_t)b * HWN + p] = s * (1.f / 64.f);
  spmax[(size_t)b * HWN + p] = mx;
}

// ---------------- K9: 7x7 conv on [mean,max] -> sigmoid ----------------------
// grid (25, 16), block 256
__global__ __launch_bounds__(256) void k_spconv(const float* __restrict__ spmean,
    const float* __restrict__ spmax, const float* __restrict__ w,
    float* __restrict__ spat) {
  const int p = blockIdx.x * 256 + threadIdx.x;
  const int b = blockIdx.y;
  const int y = p / WW, x = p - y * WW;
  const float* me = spmean + (size_t)b * HWN;
  const float* mx = spmax + (size_t)b * HWN;
  float acc = 0.f;
#pragma unroll
  for (int dy = 0; dy < 7; ++dy) {
    int yy = y + dy - 3;
    if ((unsigned)yy >= (unsigned)HH) continue;
#pragma unroll
    for (int dx = 0; dx < 7; ++dx) {
      int xx = x + dx - 3;
      if ((unsigned)xx >= (unsigned)WW) continue;
      acc = fmaf(w[dy * 7 + dx], me[yy * WW + xx], acc);
      acc = fmaf(w[49 + dy * 7 + dx], mx[yy * WW + xx], acc);
    }
  }
  spat[(size_t)b * HWN + p] = sigf(acc);
}

// ---------------- K10: fused shuffle+blend + 1x1 conv 128->256 + BN+SiLU + res
// grid (100, 4, 16), block 256
__global__ __launch_bounds__(256) void k_expand(const float* __restrict__ star1,
    const float* __restrict__ hbuf, const float* __restrict__ spat,
    const float* __restrict__ w, const float* __restrict__ bn,
    const float* __restrict__ blend, const float* __restrict__ xin,
    float* __restrict__ outp) {
  __shared__ __align__(16) float Wt[1024];
  __shared__ __align__(16) float Xt[1024];
  __shared__ float St[64];
  const int t = threadIdx.x;
  const int p0 = blockIdx.x * 64, c0 = blockIdx.y * 64, b = blockIdx.z;
  const int tx = t & 15, ty = t >> 4;
  const float alpha = sigf(blend[0]);
  const float beta = 1.f - alpha;
  if (t < 64) St[t] = spat[(size_t)b * HWN + p0 + t];
  float acc[4][4] = {};
  for (int k0 = 0; k0 < 128; k0 += 16) {
    __syncthreads();
    int idx = t;
#pragma unroll
    for (int r = 0; r < 4; ++r) {
      int c_l = idx >> 4, k_l = idx & 15;
      Wt[k_l * 64 + c_l] = w[(c0 + c_l) * 128 + k0 + k_l];
      idx += 256;
    }
    idx = t;
#pragma unroll
    for (int r = 0; r < 4; ++r) {
      int k_l = idx >> 6, p_l = idx & 63;
      int j = k0 + k_l;       // shuffled channel: even -> star, odd -> hb
      int ch = j >> 1;
      size_t o = ((size_t)b * 64 + ch) * HWN + p0 + p_l;
      float v = (j & 1) ? beta * hbuf[o] : alpha * star1[o] * St[p_l];
      Xt[k_l * 64 + p_l] = v;
      idx += 256;
    }
    __syncthreads();
#pragma unroll
    for (int kk = 0; kk < 16; ++kk) {
      const float4 wv = *reinterpret_cast<const float4*>(Wt + kk * 64 + ty * 4);
      const float4 xv = *reinterpret_cast<const float4*>(Xt + kk * 64 + tx * 4);
      const float wa[4] = {wv.x, wv.y, wv.z, wv.w};
      const float xa[4] = {xv.x, xv.y, xv.z, xv.w};
#pragma unroll
      for (int i = 0; i < 4; ++i)
#pragma unroll
        for (int j = 0; j < 4; ++j) acc[i][j] = fmaf(wa[i], xa[j], acc[i][j]);
    }
  }
#pragma unroll
  for (int i = 0; i < 4; ++i) {
    int c = c0 + ty * 4 + i;
    float s = bn[c] * rsqrtf(bn[768 + c] + 1e-5f);
    float tt = bn[256 + c] - bn[512 + c] * s;
    size_t o = ((size_t)b * 256 + c) * HWN + p0 + tx * 4;
    const float4 xres = *reinterpret_cast<const float4*>(xin + o);
    float4 ov;
    ov.x = siluf(acc[i][0] * s + tt) + xres.x;
    ov.y = siluf(acc[i][1] * s + tt) + xres.y;
    ov.z = siluf(acc[i][2] * s + tt) + xres.z;
    ov.w = siluf(acc[i][3] * s + tt) + xres.w;
    *reinterpret_cast<float4*>(outp + o) = ov;
  }
}

extern "C" void kernel_launch(void* const* d_in, const int* in_sizes, int n_in,
                              void* d_out, int out_size, void* d_ws, size_t ws_size,
                              hipStream_t stream) {
  const float* x         = (const float*)d_in[0];
  const float* w_reduce  = (const float*)d_in[1];
  const float* bn_reduce = (const float*)d_in[2];
  const float* dcn_off_w = (const float*)d_in[3];
  const float* dcn_off_b = (const float*)d_in[4];
  const float* dcn_dw_w  = (const float*)d_in[5];
  const float* dcn_pw_w  = (const float*)d_in[6];
  const float* bn_dcn    = (const float*)d_in[7];
  const float* w_d2      = (const float*)d_in[8];
  const float* bn_d2     = (const float*)d_in[9];
  const float* w_d3      = (const float*)d_in[10];
  const float* bn_d3     = (const float*)d_in[11];
  const float* w_asym1   = (const float*)d_in[12];
  const float* bn_asym1  = (const float*)d_in[13];
  const float* w_asym2   = (const float*)d_in[14];
  const float* bn_asym2  = (const float*)d_in[15];
  const float* ctx_w     = (const float*)d_in[16];
  const float* bn_star   = (const float*)d_in[17];
  const float* eca_w     = (const float*)d_in[18];
  const float* sp_w      = (const float*)d_in[19];
  const float* blend     = (const float*)d_in[20];
  const float* w_expand  = (const float*)d_in[21];
  const float* bn_expand = (const float*)d_in[22];
  float* out = (float*)d_out;
  float* ws = (float*)d_ws;

  // workspace layout (floats); liveness-based slot reuse
  float* slotA = ws;                // hs, later star1
  float* slotB = ws + BIGN;         // hb
  float* slotC = ws + 2 * BIGN;     // xd, later star0
  float* slotD = ws + 3 * BIGN;     // dw_out, later a1
  float* slotE = ws + 4 * BIGN;     // dcn
  float* sm = ws + 5 * BIGN;
  float* sx     = sm;
  float* sy     = sm + 102400;
  float* msk    = sm + 204800;
  float* spmean = sm + 307200;
  float* spmax  = sm + 409600;
  float* spat   = sm + 512000;
  float* cmean  = sm + 614400;
  float* ych    = sm + 615424;

  k_reduce<<<dim3(100, 2, 16), 256, 0, stream>>>(x, w_reduce, bn_reduce, slotA, slotB);
  k_offset<<<dim3(5, 5, 16), 256, 0, stream>>>(slotA, dcn_off_w, dcn_off_b, sx, sy, msk);
  k_gsample<<<dim3(25, 64, 16), 256, 0, stream>>>(slotA, sx, sy, msk, slotC);
  k_dw<<<dim3(25, 64, 16), 256, 0, stream>>>(slotC, dcn_dw_w, slotD);
  k_pw<<<dim3(100, 1, 16), 256, 0, stream>>>(slotD, dcn_pw_w, bn_dcn, slotE);
  k_a1<<<dim3(25, 64, 16), 256, 0, stream>>>(slotA, w_asym1, bn_asym1, slotD);
  k_ctxstar<<<dim3(25, 64, 16), 256, 0, stream>>>(slotA, slotD, slotE, w_d2, bn_d2,
                                                  w_d3, bn_d3, w_asym2, bn_asym2,
                                                  ctx_w, bn_star, slotC);
  k_cmean<<<dim3(64, 16), 256, 0, stream>>>(slotC, cmean);
  k_eca<<<dim3(1), 1024, 0, stream>>>(cmean, eca_w, ych);
  k_spstats<<<dim3(25, 16), 256, 0, stream>>>(slotC, ych, slotA, spmean, spmax);
  k_spconv<<<dim3(25, 16), 256, 0, stream>>>(spmean, spmax, sp_w, spat);
  k_expand<<<dim3(100, 4, 16), 256, 0, stream>>>(slotA, slotB, spat, w_expand,
                                                 bn_expand, blend, x, out);
}

// Round 2
// 606.795 us; speedup vs baseline: 1.1024x; 1.1024x over previous
//
#include <hip/hip_runtime.h>

#define HH 80
#define WW 80
#define HWN 6400
#define BN 16

typedef unsigned short ushortT;
typedef __attribute__((ext_vector_type(8))) short short8;
typedef __attribute__((ext_vector_type(4))) float f32x4;

static constexpr size_t BIGN = (size_t)BN * 64 * HWN;  // 6,553,600 floats

__device__ __forceinline__ float sigf(float v)  { return 1.f / (1.f + __expf(-v)); }
__device__ __forceinline__ float siluf(float v) { return v * sigf(v); }
__device__ __forceinline__ float tapf(const float* __restrict__ pl, int y, int x) {
  return ((unsigned)y < (unsigned)HH && (unsigned)x < (unsigned)WW) ? pl[y * WW + x] : 0.f;
}
__device__ __forceinline__ float bnap(float v, const float* __restrict__ bn, int c, int C) {
  float s = bn[c] * rsqrtf(bn[3 * C + c] + 1e-5f);
  return v * s + (bn[C + c] - bn[2 * C + c] * s);
}
__device__ __forceinline__ ushortT f2bf(float f) {  // RNE f32->bf16
  unsigned u = __float_as_uint(f);
  return (ushortT)((u + 0x7FFFu + ((u >> 16) & 1u)) >> 16);
}
__device__ __forceinline__ void gl_lds16(const void* g, void* l) {
  __builtin_amdgcn_global_load_lds(
      (const __attribute__((address_space(1))) unsigned int*)g,
      (__attribute__((address_space(3))) unsigned int*)l, 16, 0, 0);
}

// ---------------- K0: convert weights to bf16 --------------------------------
// grid 256, block 256: 32768 (w_reduce 128x256) + 32768 (w_expand 256x128)
__global__ __launch_bounds__(256) void k_cvtw(const float* __restrict__ wr,
    const float* __restrict__ we, ushortT* __restrict__ wrb, ushortT* __restrict__ web) {
  int i = blockIdx.x * 256 + threadIdx.x;
  if (i < 32768) wrb[i] = f2bf(wr[i]);
  else           web[i - 32768] = f2bf(we[i - 32768]);
}

// ---------------- K0b: x [b][256][6400] f32 -> xT [b][6400][256] bf16 --------
// grid (100, 16), block 256
#define XS 260
__global__ __launch_bounds__(256) void k_xpose(const float* __restrict__ x,
                                               ushortT* __restrict__ xT) {
  __shared__ ushortT T[64 * XS];
  const int t = threadIdx.x;
  const int b = blockIdx.y;
  const int p0 = blockIdx.x * 64;
  const int p4 = (t & 15) * 4, kb = t >> 4;
#pragma unroll 4
  for (int it = 0; it < 16; ++it) {
    int k = kb + it * 16;
    const float4 v = *reinterpret_cast<const float4*>(
        x + ((size_t)b * 256 + k) * HWN + p0 + p4);
    T[(p4 + 0) * XS + k] = f2bf(v.x);
    T[(p4 + 1) * XS + k] = f2bf(v.y);
    T[(p4 + 2) * XS + k] = f2bf(v.z);
    T[(p4 + 3) * XS + k] = f2bf(v.w);
  }
  __syncthreads();
#pragma unroll 4
  for (int it = 0; it < 16; ++it) {
    int idx = it * 256 + t;
    int row = idx >> 6, ch = idx & 63;
    *reinterpret_cast<uint2*>(xT + ((size_t)b * HWN + p0 + row) * 256 + ch * 4) =
        *reinterpret_cast<const uint2*>(&T[row * XS + ch * 4]);
  }
}

// ---------------- K1: MFMA GEMM 256->128 + BN + SiLU, split hs/hb ------------
// A = Wb[128][256] bf16, B = xT[b][p][256] bf16, C[c][p]. grid (50,1,16), 256 thr
__global__ __launch_bounds__(256) void k_reduce_mfma(
    const ushortT* __restrict__ xT, const ushortT* __restrict__ Wb,
    const float* __restrict__ bn, float* __restrict__ hs, float* __restrict__ hb) {
  __shared__ ushortT As[128 * 32];
  __shared__ ushortT Bs[128 * 32];
  const int t = threadIdx.x;
  const int w = t >> 6, l = t & 63;
  const int p0 = blockIdx.x * 128;
  const int b = blockIdx.z;
  const int wm = (w >> 1) * 64, wn = (w & 1) * 64;
  f32x4 acc[4][4] = {};
  const ushortT* xTb = xT + (size_t)b * HWN * 256;
  const int srow = l >> 2, scol = (l & 3) * 8;
  for (int k0 = 0; k0 < 256; k0 += 32) {
    __syncthreads();
    for (int s = w; s < 8; s += 4) {
      gl_lds16(Wb + (size_t)(s * 16 + srow) * 256 + k0 + scol, &As[s * 16 * 32]);
      gl_lds16(xTb + (size_t)(p0 + s * 16 + srow) * 256 + k0 + scol, &Bs[s * 16 * 32]);
    }
    __syncthreads();
    const int q8 = (l >> 4) * 8, r16 = l & 15;
    short8 a[4], bf[4];
#pragma unroll
    for (int i = 0; i < 4; ++i)
      a[i] = *reinterpret_cast<const short8*>(&As[(wm + i * 16 + r16) * 32 + q8]);
#pragma unroll
    for (int j = 0; j < 4; ++j)
      bf[j] = *reinterpret_cast<const short8*>(&Bs[(wn + j * 16 + r16) * 32 + q8]);
#pragma unroll
    for (int i = 0; i < 4; ++i)
#pragma unroll
      for (int j = 0; j < 4; ++j)
        acc[i][j] = __builtin_amdgcn_mfma_f32_16x16x32_bf16(a[i], bf[j], acc[i][j], 0, 0, 0);
  }
  const int col = l & 15, rowq = (l >> 4) * 4;
#pragma unroll
  for (int i = 0; i < 4; ++i) {
#pragma unroll
    for (int r = 0; r < 4; ++r) {
      int c = wm + i * 16 + rowq + r;
      float s = bn[c] * rsqrtf(bn[384 + c] + 1e-5f);
      float tt = bn[128 + c] - bn[256 + c] * s;
      float* dst = (c < 64 ? hs : hb) + ((size_t)b * 64 + (c & 63)) * HWN;
#pragma unroll
      for (int j = 0; j < 4; ++j)
        dst[p0 + wn + j * 16 + col] = siluf(acc[i][j][r] * s + tt);
    }
  }
}

// ---------------- K2: 3x3 offset conv (64->3) -> sample coords + mask --------
// grid (5, 5, 16), block 256 (16x16 tile)
__global__ __launch_bounds__(256) void k_offset(const float* __restrict__ hs,
    const float* __restrict__ w, const float* __restrict__ bias,
    float* __restrict__ sx, float* __restrict__ sy, float* __restrict__ msk) {
  __shared__ float tile[18 * 18];
  const int t = threadIdx.x;
  const int b = blockIdx.z;
  const int x0 = blockIdx.x * 16, y0 = blockIdx.y * 16;
  const int lx = t & 15, ly = t >> 4;
  float a0 = 0.f, a1 = 0.f, a2 = 0.f;
  for (int c = 0; c < 64; ++c) {
    __syncthreads();
    for (int i = t; i < 18 * 18; i += 256) {
      int tyy = i / 18, txx = i - tyy * 18;
      int gy = y0 + tyy - 1, gx = x0 + txx - 1;
      tile[i] = ((unsigned)gy < (unsigned)HH && (unsigned)gx < (unsigned)WW)
                    ? hs[((size_t)b * 64 + c) * HWN + gy * WW + gx] : 0.f;
    }
    __syncthreads();
    const float* wc = w + c * 9;
#pragma unroll
    for (int dy = 0; dy < 3; ++dy)
#pragma unroll
      for (int dx = 0; dx < 3; ++dx) {
        float v = tile[(ly + dy) * 18 + lx + dx];
        a0 = fmaf(wc[dy * 3 + dx], v, a0);
        a1 = fmaf(wc[576 + dy * 3 + dx], v, a1);
        a2 = fmaf(wc[1152 + dy * 3 + dx], v, a2);
      }
  }
  a0 += bias[0];
  a1 += bias[1];
  a2 += bias[2];
  size_t o = (size_t)b * HWN + (y0 + ly) * WW + x0 + lx;
  const float sc = 79.f / 80.f;
  sx[o] = (float)(x0 + lx) + a1 * sc;
  sy[o] = (float)(y0 + ly) + a0 * sc;
  msk[o] = sigf(a2);
}

// ---------------- K3: fused bilinear sample*mask + depthwise 3x3 -------------
// grid (25, 64, 16), block 256; LDS 18x18 halo tile of xd
__global__ __launch_bounds__(256) void k_gsdw(const float* __restrict__ hs,
    const float* __restrict__ sx, const float* __restrict__ sy,
    const float* __restrict__ msk, const float* __restrict__ wdw,
    float* __restrict__ outp) {
  __shared__ float tile[18 * 18];
  const int t = threadIdx.x;
  const int c = blockIdx.y, b = blockIdx.z;
  const int tx0 = (blockIdx.x % 5) * 16, ty0 = (blockIdx.x / 5) * 16;
  const float* pl = hs + ((size_t)b * 64 + c) * HWN;
  for (int i = t; i < 324; i += 256) {
    int iy = i / 18, ix = i - iy * 18;
    int gy = ty0 + iy - 1, gx = tx0 + ix - 1;
    float v = 0.f;
    if ((unsigned)gy < (unsigned)HH && (unsigned)gx < (unsigned)WW) {
      size_t o = (size_t)b * HWN + gy * WW + gx;
      float gxs = sx[o], gys = sy[o], m = msk[o];
      float x0f = floorf(gxs), y0f = floorf(gys);
      float wx = gxs - x0f, wy = gys - y0f;
      int ix0 = (int)x0f, iy0 = (int)y0f;
      int ix1 = ix0 + 1, iy1 = iy0 + 1;
      float acc = 0.f;
      if ((unsigned)iy0 < (unsigned)HH && (unsigned)ix0 < (unsigned)WW) acc = fmaf(pl[iy0 * WW + ix0], (1.f - wx) * (1.f - wy), acc);
      if ((unsigned)iy0 < (unsigned)HH && (unsigned)ix1 < (unsigned)WW) acc = fmaf(pl[iy0 * WW + ix1], wx * (1.f - wy), acc);
      if ((unsigned)iy1 < (unsigned)HH && (unsigned)ix0 < (unsigned)WW) acc = fmaf(pl[iy1 * WW + ix0], (1.f - wx) * wy, acc);
      if ((unsigned)iy1 < (unsigned)HH && (unsigned)ix1 < (unsigned)WW) acc = fmaf(pl[iy1 * WW + ix1], wx * wy, acc);
      v = acc * m;
    }
    tile[i] = v;
  }
  __syncthreads();
  const int lx = t & 15, ly = t >> 4;
  const float* wc = wdw + c * 9;
  float acc = 0.f;
#pragma unroll
  for (int dy = 0; dy < 3; ++dy)
#pragma unroll
    for (int dx = 0; dx < 3; ++dx)
      acc = fmaf(wc[dy * 3 + dx], tile[(ly + dy) * 18 + lx + dx], acc);
  outp[((size_t)b * 64 + c) * HWN + (ty0 + ly) * WW + tx0 + lx] = acc;
}

// ---------------- K4: 1x1 conv 64->64 + BN + SiLU (fp32) ---------------------
// grid (100, 1, 16), block 256
__global__ __launch_bounds__(256) void k_pw(const float* __restrict__ in,
    const float* __restrict__ w, const float* __restrict__ bn, float* __restrict__ outp) {
  __shared__ __align__(16) float Wt[1024];
  __shared__ __align__(16) float Xt[1024];
  const int t = threadIdx.x;
  const int p0 = blockIdx.x * 64, b = blockIdx.z;
  const int tx = t & 15, ty = t >> 4;
  float acc[4][4] = {};
  for (int k0 = 0; k0 < 64; k0 += 16) {
    __syncthreads();
    int idx = t;
#pragma unroll
    for (int r = 0; r < 4; ++r) {
      int c_l = idx >> 4, k_l = idx & 15;
      Wt[k_l * 64 + c_l] = w[c_l * 64 + k0 + k_l];
      idx += 256;
    }
    idx = t;
#pragma unroll
    for (int r = 0; r < 4; ++r) {
      int k_l = idx >> 6, p_l = idx & 63;
      Xt[k_l * 64 + p_l] = in[((size_t)b * 64 + k0 + k_l) * HWN + p0 + p_l];
      idx += 256;
    }
    __syncthreads();
#pragma unroll
    for (int kk = 0; kk < 16; ++kk) {
      const float4 wv = *reinterpret_cast<const float4*>(Wt + kk * 64 + ty * 4);
      const float4 xv = *reinterpret_cast<const float4*>(Xt + kk * 64 + tx * 4);
      const float wa[4] = {wv.x, wv.y, wv.z, wv.w};
      const float xa[4] = {xv.x, xv.y, xv.z, xv.w};
#pragma unroll
      for (int i = 0; i < 4; ++i)
#pragma unroll
        for (int j = 0; j < 4; ++j) acc[i][j] = fmaf(wa[i], xa[j], acc[i][j]);
    }
  }
#pragma unroll
  for (int i = 0; i < 4; ++i) {
    int c = ty * 4 + i;
    float s = bn[c] * rsqrtf(bn[192 + c] + 1e-5f);
    float tt = bn[64 + c] - bn[128 + c] * s;
    float4 o;
    o.x = siluf(acc[i][0] * s + tt);
    o.y = siluf(acc[i][1] * s + tt);
    o.z = siluf(acc[i][2] * s + tt);
    o.w = siluf(acc[i][3] * s + tt);
    *reinterpret_cast<float4*>(outp + ((size_t)b * 64 + c) * HWN + p0 + tx * 4) = o;
  }
}

// ---------------- K5: depthwise 1x7 + BN + SiLU -> a1 ------------------------
__global__ __launch_bounds__(256) void k_a1(const float* __restrict__ hs,
    const float* __restrict__ w, const float* __restrict__ bn, float* __restrict__ a1) {
  const int p = blockIdx.x * 256 + threadIdx.x;
  const int c = blockIdx.y, b = blockIdx.z;
  const int y = p / WW, x = p - y * WW;
  const float* pl = hs + ((size_t)b * 64 + c) * HWN;
  const float* wc = w + c * 7;
  float acc = 0.f;
#pragma unroll
  for (int k = 0; k < 7; ++k) acc = fmaf(wc[k], tapf(pl, y, x + k - 3), acc);
  a1[((size_t)b * 64 + c) * HWN + p] = siluf(bnap(acc, bn, c, 64));
}

// ---------------- K6: d2 + d3 + asym -> ctx; star0 = BN(dcn*ctx) in-place ----
__global__ __launch_bounds__(256) void k_ctxstar(const float* __restrict__ hs,
    const float* __restrict__ a1, const float* __restrict__ dcn,
    const float* __restrict__ wd2, const float* __restrict__ bnd2,
    const float* __restrict__ wd3, const float* __restrict__ bnd3,
    const float* __restrict__ wa2, const float* __restrict__ bna2,
    const float* __restrict__ cw, const float* __restrict__ bnstar,
    float* __restrict__ star0) {
  const int p = blockIdx.x * 256 + threadIdx.x;
  const int c = blockIdx.y, b = blockIdx.z;
  const int y = p / WW, x = p - y * WW;
  const float* pl = hs + ((size_t)b * 64 + c) * HWN;
  float d2 = 0.f, d3 = 0.f;
#pragma unroll
  for (int dy = 0; dy < 3; ++dy)
#pragma unroll
    for (int dx = 0; dx < 3; ++dx) {
      d2 = fmaf(wd2[c * 9 + dy * 3 + dx], tapf(pl, y + 2 * (dy - 1), x + 2 * (dx - 1)), d2);
      d3 = fmaf(wd3[c * 9 + dy * 3 + dx], tapf(pl, y + 3 * (dy - 1), x + 3 * (dx - 1)), d3);
    }
  const float* ap = a1 + ((size_t)b * 64 + c) * HWN;
  float as = 0.f;
#pragma unroll
  for (int k = 0; k < 7; ++k) as = fmaf(wa2[c * 7 + k], tapf(ap, y + k - 3, x), as);
  d2 = siluf(bnap(d2, bnd2, c, 64));
  d3 = siluf(bnap(d3, bnd3, c, 64));
  as = siluf(bnap(as, bna2, c, 64));
  float e0 = __expf(cw[0]), e1 = __expf(cw[1]), e2 = __expf(cw[2]);
  float inv = 1.f / (e0 + e1 + e2);
  float ctx = (e0 * d2 + e1 * d3 + e2 * as) * inv;
  float dv = dcn[((size_t)b * 64 + c) * HWN + p];
  star0[((size_t)b * 64 + c) * HWN + p] = bnap(dv * ctx, bnstar, c, 64);
}

// ---------------- K7: per-(b,c) spatial mean of star0 ------------------------
__global__ __launch_bounds__(256) void k_cmean(const float* __restrict__ star0,
    float* __restrict__ mean) {
  const int c = blockIdx.x, b = blockIdx.y;
  const float* pl = star0 + ((size_t)b * 64 + c) * HWN;
  float s = 0.f;
  for (int i = threadIdx.x; i < HWN; i += 256) s += pl[i];
  __shared__ float red[256];
  red[threadIdx.x] = s;
  __syncthreads();
  for (int st = 128; st > 0; st >>= 1) {
    if (threadIdx.x < st) red[threadIdx.x] += red[threadIdx.x + st];
    __syncthreads();
  }
  if (threadIdx.x == 0) mean[b * 64 + c] = red[0] * (1.f / HWN);
}

// ---------------- K7b: ECA + sigmoid -----------------------------------------
__global__ __launch_bounds__(1024) void k_eca(const float* __restrict__ mean,
    const float* __restrict__ ew, float* __restrict__ ych) {
  const int t = threadIdx.x;
  const int c = t & 63;
  const int base = t - c;
  float acc = 0.f;
#pragma unroll
  for (int k = 0; k < 5; ++k) {
    int cc = c + k - 2;
    if ((unsigned)cc < 64u) acc = fmaf(ew[k], mean[base + cc], acc);
  }
  ych[t] = sigf(acc);
}

// ---------------- K8: channel mean/max of star0*ych (no star1 store) ---------
// grid (25, 16), block 256
__global__ __launch_bounds__(256) void k_spstats(const float* __restrict__ star0,
    const float* __restrict__ ych, float* __restrict__ spmean, float* __restrict__ spmax) {
  __shared__ float yc[64];
  if (threadIdx.x < 64) yc[threadIdx.x] = ych[blockIdx.y * 64 + threadIdx.x];
  __syncthreads();
  const int p = blockIdx.x * 256 + threadIdx.x;
  const int b = blockIdx.y;
  float s = 0.f, mx = -1e30f;
  for (int c = 0; c < 64; ++c) {
    float v = star0[((size_t)b * 64 + c) * HWN + p] * yc[c];
    s += v;
    mx = fmaxf(mx, v);
  }
  spmean[(size_t)b * HWN + p] = s * (1.f / 64.f);
  spmax[(size_t)b * HWN + p] = mx;
}

// ---------------- K9: 7x7 conv on [mean,max] -> sigmoid ----------------------
__global__ __launch_bounds__(256) void k_spconv(const float* __restrict__ spmean,
    const float* __restrict__ spmax, const float* __restrict__ w,
    float* __restrict__ spat) {
  const int p = blockIdx.x * 256 + threadIdx.x;
  const int b = blockIdx.y;
  const int y = p / WW, x = p - y * WW;
  const float* me = spmean + (size_t)b * HWN;
  const float* mx = spmax + (size_t)b * HWN;
  float acc = 0.f;
#pragma unroll
  for (int dy = 0; dy < 7; ++dy) {
    int yy = y + dy - 3;
    if ((unsigned)yy >= (unsigned)HH) continue;
#pragma unroll
    for (int dx = 0; dx < 7; ++dx) {
      int xx = x + dx - 3;
      if ((unsigned)xx >= (unsigned)WW) continue;
      acc = fmaf(w[dy * 7 + dx], me[yy * WW + xx], acc);
      acc = fmaf(w[49 + dy * 7 + dx], mx[yy * WW + xx], acc);
    }
  }
  spat[(size_t)b * HWN + p] = sigf(acc);
}

// ---------------- K10: build expand B operand, bf16 [b][p][128] --------------
// BT[p][2c] = alpha*spat[p]*star0[c][p]*ych[c]; BT[p][2c+1] = (1-alpha)*hb[c][p]
// grid (100, 16), block 256; LDS 64 x 132 ushort
__global__ __launch_bounds__(256) void k_mkB(const float* __restrict__ star0,
    const float* __restrict__ ych, const float* __restrict__ spat,
    const float* __restrict__ hb, const float* __restrict__ blend,
    ushortT* __restrict__ BT) {
  __shared__ ushortT T[64 * 132];
  const int t = threadIdx.x;
  const int b = blockIdx.y;
  const int p0 = blockIdx.x * 64;
  const float alpha = sigf(blend[0]);
  const float beta = 1.f - alpha;
  const int pl = t & 63;
  const int w = t >> 6;
  const float sp = alpha * spat[(size_t)b * HWN + p0 + pl];
  for (int c = w * 16; c < w * 16 + 16; ++c) {
    size_t o = ((size_t)b * 64 + c) * HWN + p0 + pl;
    unsigned lo = f2bf(star0[o] * ych[b * 64 + c] * sp);
    unsigned hi = f2bf(beta * hb[o]);
    *reinterpret_cast<unsigned*>(&T[pl * 132 + 2 * c]) = lo | (hi << 16);
  }
  __syncthreads();
#pragma unroll
  for (int it = 0; it < 8; ++it) {
    int idx = it * 256 + t;
    int row = idx >> 5, ch = idx & 31;
    *reinterpret_cast<uint2*>(&BT[((size_t)b * HWN + p0 + row) * 128 + ch * 4]) =
        *reinterpret_cast<const uint2*>(&T[row * 132 + ch * 4]);
  }
}

// ---------------- K11: MFMA GEMM 128->256 + BN + SiLU + residual -------------
// grid (50, 2, 16), block 256
__global__ __launch_bounds__(256) void k_expand_mfma(
    const ushortT* __restrict__ BT, const ushortT* __restrict__ Wb,
    const float* __restrict__ bn, const float* __restrict__ xin,
    float* __restrict__ outp) {
  __shared__ ushortT As[128 * 32];
  __shared__ ushortT Bs[128 * 32];
  const int t = threadIdx.x;
  const int w = t >> 6, l = t & 63;
  const int p0 = blockIdx.x * 128;
  const int c0 = blockIdx.y * 128;
  const int b = blockIdx.z;
  const int wm = (w >> 1) * 64, wn = (w & 1) * 64;
  f32x4 acc[4][4] = {};
  const ushortT* BTb = BT + (size_t)b * HWN * 128;
  const int srow = l >> 2, scol = (l & 3) * 8;
  for (int k0 = 0; k0 < 128; k0 += 32) {
    __syncthreads();
    for (int s = w; s < 8; s += 4) {
      gl_lds16(Wb + (size_t)(c0 + s * 16 + srow) * 128 + k0 + scol, &As[s * 16 * 32]);
      gl_lds16(BTb + (size_t)(p0 + s * 16 + srow) * 128 + k0 + scol, &Bs[s * 16 * 32]);
    }
    __syncthreads();
    const int q8 = (l >> 4) * 8, r16 = l & 15;
    short8 a[4], bf[4];
#pragma unroll
    for (int i = 0; i < 4; ++i)
      a[i] = *reinterpret_cast<const short8*>(&As[(wm + i * 16 + r16) * 32 + q8]);
#pragma unroll
    for (int j = 0; j < 4; ++j)
      bf[j] = *reinterpret_cast<const short8*>(&Bs[(wn + j * 16 + r16) * 32 + q8]);
#pragma unroll
    for (int i = 0; i < 4; ++i)
#pragma unroll
      for (int j = 0; j < 4; ++j)
        acc[i][j] = __builtin_amdgcn_mfma_f32_16x16x32_bf16(a[i], bf[j], acc[i][j], 0, 0, 0);
  }
  const int col = l & 15, rowq = (l >> 4) * 4;
#pragma unroll
  for (int i = 0; i < 4; ++i) {
#pragma unroll
    for (int r = 0; r < 4; ++r) {
      int c = c0 + wm + i * 16 + rowq + r;
      float s = bn[c] * rsqrtf(bn[768 + c] + 1e-5f);
      float tt = bn[256 + c] - bn[512 + c] * s;
      size_t rowo = ((size_t)b * 256 + c) * HWN;
#pragma unroll
      for (int j = 0; j < 4; ++j) {
        int p = p0 + wn + j * 16 + col;
        outp[rowo + p] = siluf(acc[i][j][r] * s + tt) + xin[rowo + p];
      }
    }
  }
}

extern "C" void kernel_launch(void* const* d_in, const int* in_sizes, int n_in,
                              void* d_out, int out_size, void* d_ws, size_t ws_size,
                              hipStream_t stream) {
  const float* x         = (const float*)d_in[0];
  const float* w_reduce  = (const float*)d_in[1];
  const float* bn_reduce = (const float*)d_in[2];
  const float* dcn_off_w = (const float*)d_in[3];
  const float* dcn_off_b = (const float*)d_in[4];
  const float* dcn_dw_w  = (const float*)d_in[5];
  const float* dcn_pw_w  = (const float*)d_in[6];
  const float* bn_dcn    = (const float*)d_in[7];
  const float* w_d2      = (const float*)d_in[8];
  const float* bn_d2     = (const float*)d_in[9];
  const float* w_d3      = (const float*)d_in[10];
  const float* bn_d3     = (const float*)d_in[11];
  const float* w_asym1   = (const float*)d_in[12];
  const float* bn_asym1  = (const float*)d_in[13];
  const float* w_asym2   = (const float*)d_in[14];
  const float* bn_asym2  = (const float*)d_in[15];
  const float* ctx_w     = (const float*)d_in[16];
  const float* bn_star   = (const float*)d_in[17];
  const float* eca_w     = (const float*)d_in[18];
  const float* sp_w      = (const float*)d_in[19];
  const float* blend     = (const float*)d_in[20];
  const float* w_expand  = (const float*)d_in[21];
  const float* bn_expand = (const float*)d_in[22];
  float* out = (float*)d_out;
  float* ws = (float*)d_ws;

  // workspace layout (floats), liveness-based reuse; total 132.4 MB
  float* slotA = ws;                    // hs
  float* slotB = ws + BIGN;             // hb
  float* slotC = ws + 2 * BIGN;         // dwout, later a1
  float* slotD = ws + 3 * BIGN;         // dcn, later star0 (in-place)
  ushortT* BT  = (ushortT*)(ws + 4 * BIGN);            // 13,107,200 ushort
  ushortT* Wrb = (ushortT*)(ws + 5 * BIGN);            // 32768 ushort
  ushortT* Web = (ushortT*)(ws + 5 * BIGN + 16384);    // 32768 ushort
  float* sm = ws + 5 * BIGN + 32768;
  float* sx     = sm;                 // alias spmean (disjoint lifetime)
  float* sy     = sm + 102400;        // alias spmax
  float* msk    = sm + 204800;        // alias spat
  float* spmean = sx;
  float* spmax  = sy;
  float* spat   = msk;
  float* cmean  = sm + 307200;
  float* ych    = sm + 308224;
  ushortT* xT = (ushortT*)d_out;      // 52.4 MB scratch inside d_out (dead until K11)

  k_cvtw<<<dim3(256), 256, 0, stream>>>(w_reduce, w_expand, Wrb, Web);
  k_xpose<<<dim3(100, 16), 256, 0, stream>>>(x, xT);
  k_reduce_mfma<<<dim3(50, 1, 16), 256, 0, stream>>>(xT, Wrb, bn_reduce, slotA, slotB);
  k_offset<<<dim3(5, 5, 16), 256, 0, stream>>>(slotA, dcn_off_w, dcn_off_b, sx, sy, msk);
  k_gsdw<<<dim3(25, 64, 16), 256, 0, stream>>>(slotA, sx, sy, msk, dcn_dw_w, slotC);
  k_pw<<<dim3(100, 1, 16), 256, 0, stream>>>(slotC, dcn_pw_w, bn_dcn, slotD);
  k_a1<<<dim3(25, 64, 16), 256, 0, stream>>>(slotA, w_asym1, bn_asym1, slotC);
  k_ctxstar<<<dim3(25, 64, 16), 256, 0, stream>>>(slotA, slotC, slotD, w_d2, bn_d2,
                                                  w_d3, bn_d3, w_asym2, bn_asym2,
                                                  ctx_w, bn_star, slotD);
  k_cmean<<<dim3(64, 16), 256, 0, stream>>>(slotD, cmean);
  k_eca<<<dim3(1), 1024, 0, stream>>>(cmean, eca_w, ych);
  k_spstats<<<dim3(25, 16), 256, 0, stream>>>(slotD, ych, spmean, spmax);
  k_spconv<<<dim3(25, 16), 256, 0, stream>>>(spmean, spmax, sp_w, spat);
  k_mkB<<<dim3(100, 16), 256, 0, stream>>>(slotD, ych, spat, slotB, blend, BT);
  k_expand_mfma<<<dim3(50, 2, 16), 256, 0, stream>>>(BT, Web, bn_expand, x, out);
}

// Round 3
// 518.318 us; speedup vs baseline: 1.2905x; 1.1707x over previous
//
#include <hip/hip_runtime.h>

#define HH 80
#define WW 80
#define HWN 6400
#define BN 16

typedef unsigned short ushortT;
typedef __attribute__((ext_vector_type(8))) short short8;
typedef __attribute__((ext_vector_type(4))) float f32x4;

static constexpr size_t BIGN = (size_t)BN * 64 * HWN;  // 6,553,600 floats

__device__ __forceinline__ float sigf(float v)  { return 1.f / (1.f + __expf(-v)); }
__device__ __forceinline__ float siluf(float v) { return v * sigf(v); }
__device__ __forceinline__ float tapf(const float* __restrict__ pl, int y, int x) {
  return ((unsigned)y < (unsigned)HH && (unsigned)x < (unsigned)WW) ? pl[y * WW + x] : 0.f;
}
__device__ __forceinline__ float bnap(float v, const float* __restrict__ bn, int c, int C) {
  float s = bn[c] * rsqrtf(bn[3 * C + c] + 1e-5f);
  return v * s + (bn[C + c] - bn[2 * C + c] * s);
}
__device__ __forceinline__ ushortT f2bf(float f) {  // RNE f32->bf16
  unsigned u = __float_as_uint(f);
  return (ushortT)((u + 0x7FFFu + ((u >> 16) & 1u)) >> 16);
}
__device__ __forceinline__ void gl_lds16(const void* g, void* l) {
  __builtin_amdgcn_global_load_lds(
      (const __attribute__((address_space(1))) unsigned int*)g,
      (__attribute__((address_space(3))) unsigned int*)l, 16, 0, 0);
}
// Bs LDS addressing: [p][k2] uints, row stride 20, 16B-chunk XOR swizzle.
// write: uint index for (p, k2); read: base uint index of 16B chunk q for row p.
__device__ __forceinline__ int bs_w(int p, int k2) {
  return p * 20 + ((((k2 >> 2) ^ ((p >> 3) & 3)) << 2) | (k2 & 3));
}
__device__ __forceinline__ int bs_r(int p, int q) {
  return p * 20 + (((q ^ ((p >> 3) & 3)) << 2));
}

// ---------------- K0: convert GEMM weights to bf16 ---------------------------
__global__ __launch_bounds__(256) void k_cvtw(const float* __restrict__ wr,
    const float* __restrict__ we, ushortT* __restrict__ wrb, ushortT* __restrict__ web) {
  int i = blockIdx.x * 256 + threadIdx.x;
  if (i < 32768) wrb[i] = f2bf(wr[i]);
  else           web[i - 32768] = f2bf(we[i - 32768]);
}

// ---------------- K1: MFMA GEMM 256->128 + BN + SiLU, fused transpose --------
// C[c][p] = sum_k W[c][k] * x[b][k][p]; tile 128c x 128p, K=256 in 8 chunks.
// grid (50, 1, 16), block 256 (4 waves, each 64c x 64p)
__global__ __launch_bounds__(256) void k_reduce_mfma(
    const float* __restrict__ x, const ushortT* __restrict__ Wb,
    const float* __restrict__ bn, float* __restrict__ hs, float* __restrict__ hb) {
  __shared__ ushortT As[128 * 32];       // [c][k] bf16, stride 32
  __shared__ unsigned BsU[128 * 20];     // [p][k2] swizzled
  __shared__ float Ep[4 * 16 * 66];      // per-wave epilogue transpose
  const int t = threadIdx.x;
  const int w = t >> 6, l = t & 63;
  const int p0 = blockIdx.x * 128;
  const int b = blockIdx.z;
  const int wm = (w >> 1) * 64, wn = (w & 1) * 64;
  f32x4 acc[4][4] = {};
  const float* xb = x + (size_t)b * 256 * HWN;
  const int srow = l >> 2, scol = (l & 3) * 8;
  for (int k0 = 0; k0 < 256; k0 += 32) {
    __syncthreads();
    gl_lds16(Wb + (size_t)((w * 2) * 16 + srow) * 256 + k0 + scol, &As[(w * 2) * 16 * 32]);
    gl_lds16(Wb + (size_t)((w * 2 + 1) * 16 + srow) * 256 + k0 + scol, &As[(w * 2 + 1) * 16 * 32]);
#pragma unroll
    for (int pass = 0; pass < 8; ++pass) {
      int idx = pass * 256 + t;
      int p_l = idx & 127, k2 = idx >> 7;
      int k = k0 + 2 * k2;
      float v0 = xb[(size_t)k * HWN + p0 + p_l];
      float v1 = xb[(size_t)(k + 1) * HWN + p0 + p_l];
      BsU[bs_w(p_l, k2)] = (unsigned)f2bf(v0) | ((unsigned)f2bf(v1) << 16);
    }
    __syncthreads();
    const int q = l >> 4, r16 = l & 15;
    short8 a[4], bv[4];
#pragma unroll
    for (int i = 0; i < 4; ++i)
      a[i] = *reinterpret_cast<const short8*>(&As[(wm + i * 16 + r16) * 32 + q * 8]);
#pragma unroll
    for (int j = 0; j < 4; ++j) {
      int row = wn + j * 16 + r16;
      bv[j] = *reinterpret_cast<const short8*>(&BsU[bs_r(row, q)]);
    }
#pragma unroll
    for (int i = 0; i < 4; ++i)
#pragma unroll
      for (int j = 0; j < 4; ++j)
        acc[i][j] = __builtin_amdgcn_mfma_f32_16x16x32_bf16(a[i], bv[j], acc[i][j], 0, 0, 0);
  }
  // epilogue: per-wave LDS transpose -> coalesced float4 stores
  float* T = Ep + w * (16 * 66);
  const int col = l & 15, rowq = (l >> 4) * 4;
#pragma unroll
  for (int i = 0; i < 4; ++i) {
#pragma unroll
    for (int r = 0; r < 4; ++r)
#pragma unroll
      for (int j = 0; j < 4; ++j)
        T[(rowq + r) * 66 + j * 16 + col] = acc[i][j][r];
#pragma unroll
    for (int pass = 0; pass < 4; ++pass) {
      int row_l = pass * 4 + (l >> 4);
      const float4 v = *reinterpret_cast<const float4*>(&T[row_l * 66 + col * 4]);
      int c = wm + i * 16 + row_l;
      float s = bn[c] * rsqrtf(bn[384 + c] + 1e-5f);
      float tt = bn[128 + c] - bn[256 + c] * s;
      float4 o;
      o.x = siluf(v.x * s + tt);
      o.y = siluf(v.y * s + tt);
      o.z = siluf(v.z * s + tt);
      o.w = siluf(v.w * s + tt);
      float* dst = (c < 64 ? hs : hb) + ((size_t)b * 64 + (c & 63)) * HWN + p0 + wn + col * 4;
      *reinterpret_cast<float4*>(dst) = o;
    }
  }
}

// ---------------- K2: 3x3 offset conv (64->3) -> sample coords + mask --------
// grid (5, 5, 16), block 256 (16x16 tile)
__global__ __launch_bounds__(256) void k_offset(const float* __restrict__ hs,
    const float* __restrict__ w, const float* __restrict__ bias,
    float* __restrict__ sx, float* __restrict__ sy, float* __restrict__ msk) {
  __shared__ float tile[18 * 18];
  const int t = threadIdx.x;
  const int b = blockIdx.z;
  const int x0 = blockIdx.x * 16, y0 = blockIdx.y * 16;
  const int lx = t & 15, ly = t >> 4;
  float a0 = 0.f, a1 = 0.f, a2 = 0.f;
  for (int c = 0; c < 64; ++c) {
    __syncthreads();
    for (int i = t; i < 18 * 18; i += 256) {
      int tyy = i / 18, txx = i - tyy * 18;
      int gy = y0 + tyy - 1, gx = x0 + txx - 1;
      tile[i] = ((unsigned)gy < (unsigned)HH && (unsigned)gx < (unsigned)WW)
                    ? hs[((size_t)b * 64 + c) * HWN + gy * WW + gx] : 0.f;
    }
    __syncthreads();
    const float* wc = w + c * 9;
#pragma unroll
    for (int dy = 0; dy < 3; ++dy)
#pragma unroll
      for (int dx = 0; dx < 3; ++dx) {
        float v = tile[(ly + dy) * 18 + lx + dx];
        a0 = fmaf(wc[dy * 3 + dx], v, a0);
        a1 = fmaf(wc[576 + dy * 3 + dx], v, a1);
        a2 = fmaf(wc[1152 + dy * 3 + dx], v, a2);
      }
  }
  a0 += bias[0];
  a1 += bias[1];
  a2 += bias[2];
  size_t o = (size_t)b * HWN + (y0 + ly) * WW + x0 + lx;
  const float sc = 79.f / 80.f;
  sx[o] = (float)(x0 + lx) + a1 * sc;
  sy[o] = (float)(y0 + ly) + a0 * sc;
  msk[o] = sigf(a2);
}

// ---------------- K3: fused bilinear sample*mask + depthwise 3x3 -------------
__global__ __launch_bounds__(256) void k_gsdw(const float* __restrict__ hs,
    const float* __restrict__ sx, const float* __restrict__ sy,
    const float* __restrict__ msk, const float* __restrict__ wdw,
    float* __restrict__ outp) {
  __shared__ float tile[18 * 18];
  const int t = threadIdx.x;
  const int c = blockIdx.y, b = blockIdx.z;
  const int tx0 = (blockIdx.x % 5) * 16, ty0 = (blockIdx.x / 5) * 16;
  const float* pl = hs + ((size_t)b * 64 + c) * HWN;
  for (int i = t; i < 324; i += 256) {
    int iy = i / 18, ix = i - iy * 18;
    int gy = ty0 + iy - 1, gx = tx0 + ix - 1;
    float v = 0.f;
    if ((unsigned)gy < (unsigned)HH && (unsigned)gx < (unsigned)WW) {
      size_t o = (size_t)b * HWN + gy * WW + gx;
      float gxs = sx[o], gys = sy[o], m = msk[o];
      float x0f = floorf(gxs), y0f = floorf(gys);
      float wx = gxs - x0f, wy = gys - y0f;
      int ix0 = (int)x0f, iy0 = (int)y0f;
      int ix1 = ix0 + 1, iy1 = iy0 + 1;
      float acc = 0.f;
      if ((unsigned)iy0 < (unsigned)HH && (unsigned)ix0 < (unsigned)WW) acc = fmaf(pl[iy0 * WW + ix0], (1.f - wx) * (1.f - wy), acc);
      if ((unsigned)iy0 < (unsigned)HH && (unsigned)ix1 < (unsigned)WW) acc = fmaf(pl[iy0 * WW + ix1], wx * (1.f - wy), acc);
      if ((unsigned)iy1 < (unsigned)HH && (unsigned)ix0 < (unsigned)WW) acc = fmaf(pl[iy1 * WW + ix0], (1.f - wx) * wy, acc);
      if ((unsigned)iy1 < (unsigned)HH && (unsigned)ix1 < (unsigned)WW) acc = fmaf(pl[iy1 * WW + ix1], wx * wy, acc);
      v = acc * m;
    }
    tile[i] = v;
  }
  __syncthreads();
  const int lx = t & 15, ly = t >> 4;
  const float* wc = wdw + c * 9;
  float acc = 0.f;
#pragma unroll
  for (int dy = 0; dy < 3; ++dy)
#pragma unroll
    for (int dx = 0; dx < 3; ++dx)
      acc = fmaf(wc[dy * 3 + dx], tile[(ly + dy) * 18 + lx + dx], acc);
  outp[((size_t)b * 64 + c) * HWN + (ty0 + ly) * WW + tx0 + lx] = acc;
}

// ---------------- K4: 1x1 conv 64->64 + BN + SiLU (fp32) ---------------------
__global__ __launch_bounds__(256) void k_pw(const float* __restrict__ in,
    const float* __restrict__ w, const float* __restrict__ bn, float* __restrict__ outp) {
  __shared__ __align__(16) float Wt[1024];
  __shared__ __align__(16) float Xt[1024];
  const int t = threadIdx.x;
  const int p0 = blockIdx.x * 64, b = blockIdx.z;
  const int tx = t & 15, ty = t >> 4;
  float acc[4][4] = {};
  for (int k0 = 0; k0 < 64; k0 += 16) {
    __syncthreads();
    int idx = t;
#pragma unroll
    for (int r = 0; r < 4; ++r) {
      int c_l = idx >> 4, k_l = idx & 15;
      Wt[k_l * 64 + c_l] = w[c_l * 64 + k0 + k_l];
      idx += 256;
    }
    idx = t;
#pragma unroll
    for (int r = 0; r < 4; ++r) {
      int k_l = idx >> 6, p_l = idx & 63;
      Xt[k_l * 64 + p_l] = in[((size_t)b * 64 + k0 + k_l) * HWN + p0 + p_l];
      idx += 256;
    }
    __syncthreads();
#pragma unroll
    for (int kk = 0; kk < 16; ++kk) {
      const float4 wv = *reinterpret_cast<const float4*>(Wt + kk * 64 + ty * 4);
      const float4 xv = *reinterpret_cast<const float4*>(Xt + kk * 64 + tx * 4);
      const float wa[4] = {wv.x, wv.y, wv.z, wv.w};
      const float xa[4] = {xv.x, xv.y, xv.z, xv.w};
#pragma unroll
      for (int i = 0; i < 4; ++i)
#pragma unroll
        for (int j = 0; j < 4; ++j) acc[i][j] = fmaf(wa[i], xa[j], acc[i][j]);
    }
  }
#pragma unroll
  for (int i = 0; i < 4; ++i) {
    int c = ty * 4 + i;
    float s = bn[c] * rsqrtf(bn[192 + c] + 1e-5f);
    float tt = bn[64 + c] - bn[128 + c] * s;
    float4 o;
    o.x = siluf(acc[i][0] * s + tt);
    o.y = siluf(acc[i][1] * s + tt);
    o.z = siluf(acc[i][2] * s + tt);
    o.w = siluf(acc[i][3] * s + tt);
    *reinterpret_cast<float4*>(outp + ((size_t)b * 64 + c) * HWN + p0 + tx * 4) = o;
  }
}

// ---------------- K5: fused a1 + d2 + d3 + asym -> ctx; star0 = BN(dcn*ctx) --
// grid (25, 64, 16), block 256 (16x16 tile); hs halo +-3 in LDS, a1 in LDS
__global__ __launch_bounds__(256) void k_ctxstar(const float* __restrict__ hs,
    const float* __restrict__ dcn,
    const float* __restrict__ wd2, const float* __restrict__ bnd2,
    const float* __restrict__ wd3, const float* __restrict__ bnd3,
    const float* __restrict__ wa1, const float* __restrict__ bna1,
    const float* __restrict__ wa2, const float* __restrict__ bna2,
    const float* __restrict__ cw, const float* __restrict__ bnstar,
    float* __restrict__ star0) {
  __shared__ float ht[22 * 23];   // hs tile, rows/cols offset -3
  __shared__ float at[22 * 17];   // a1 tile: 22 rows (y-3..y+18) x 16 cols
  const int t = threadIdx.x;
  const int c = blockIdx.y, b = blockIdx.z;
  const int tx0 = (blockIdx.x % 5) * 16, ty0 = (blockIdx.x / 5) * 16;
  const float* pl = hs + ((size_t)b * 64 + c) * HWN;
  for (int i = t; i < 484; i += 256) {
    int iy = i / 22, ix = i - iy * 22;
    int gy = ty0 + iy - 3, gx = tx0 + ix - 3;
    ht[iy * 23 + ix] = ((unsigned)gy < (unsigned)HH && (unsigned)gx < (unsigned)WW)
                           ? pl[gy * WW + gx] : 0.f;
  }
  __syncthreads();
  // a1 = silu(bn(1x7 dw)) on 22 rows x 16 cols
  for (int i = t; i < 352; i += 256) {
    int iy = i >> 4, ix = i & 15;
    int gy = ty0 + iy - 3;
    float v = 0.f;
    if ((unsigned)gy < (unsigned)HH) {
      float s = 0.f;
#pragma unroll
      for (int k = 0; k < 7; ++k) s = fmaf(wa1[c * 7 + k], ht[iy * 23 + ix + k], s);
      v = siluf(bnap(s, bna1, c, 64));
    }
    at[iy * 17 + ix] = v;
  }
  __syncthreads();
  const int lx = t & 15, ly = t >> 4;
  float d2 = 0.f, d3 = 0.f;
#pragma unroll
  for (int dy = 0; dy < 3; ++dy)
#pragma unroll
    for (int dx = 0; dx < 3; ++dx) {
      float w2 = wd2[c * 9 + dy * 3 + dx], w3 = wd3[c * 9 + dy * 3 + dx];
      d2 = fmaf(w2, ht[(ly + 3 + 2 * (dy - 1)) * 23 + lx + 3 + 2 * (dx - 1)], d2);
      d3 = fmaf(w3, ht[(ly + 3 + 3 * (dy - 1)) * 23 + lx + 3 + 3 * (dx - 1)], d3);
    }
  float as = 0.f;
#pragma unroll
  for (int k = 0; k < 7; ++k) as = fmaf(wa2[c * 7 + k], at[(ly + k) * 17 + lx], as);
  d2 = siluf(bnap(d2, bnd2, c, 64));
  d3 = siluf(bnap(d3, bnd3, c, 64));
  as = siluf(bnap(as, bna2, c, 64));
  float e0 = __expf(cw[0]), e1 = __expf(cw[1]), e2 = __expf(cw[2]);
  float inv = 1.f / (e0 + e1 + e2);
  float ctx = (e0 * d2 + e1 * d3 + e2 * as) * inv;
  size_t o = ((size_t)b * 64 + c) * HWN + (ty0 + ly) * WW + tx0 + lx;
  star0[o] = bnap(dcn[o] * ctx, bnstar, c, 64);
}

// ---------------- K6: per-(b,c) spatial mean of star0 ------------------------
__global__ __launch_bounds__(256) void k_cmean(const float* __restrict__ star0,
    float* __restrict__ mean) {
  const int c = blockIdx.x, b = blockIdx.y;
  const float* pl = star0 + ((size_t)b * 64 + c) * HWN;
  float s = 0.f;
  for (int i = threadIdx.x; i < HWN; i += 256) s += pl[i];
  __shared__ float red[256];
  red[threadIdx.x] = s;
  __syncthreads();
  for (int st = 128; st > 0; st >>= 1) {
    if (threadIdx.x < st) red[threadIdx.x] += red[threadIdx.x + st];
    __syncthreads();
  }
  if (threadIdx.x == 0) mean[b * 64 + c] = red[0] * (1.f / HWN);
}

// ---------------- K6b: ECA + sigmoid -----------------------------------------
__global__ __launch_bounds__(1024) void k_eca(const float* __restrict__ mean,
    const float* __restrict__ ew, float* __restrict__ ych) {
  const int t = threadIdx.x;
  const int c = t & 63;
  const int base = t - c;
  float acc = 0.f;
#pragma unroll
  for (int k = 0; k < 5; ++k) {
    int cc = c + k - 2;
    if ((unsigned)cc < 64u) acc = fmaf(ew[k], mean[base + cc], acc);
  }
  ych[t] = sigf(acc);
}

// ---------------- K7: channel mean/max of star0*ych --------------------------
__global__ __launch_bounds__(256) void k_spstats(const float* __restrict__ star0,
    const float* __restrict__ ych, float* __restrict__ spmean, float* __restrict__ spmax) {
  __shared__ float yc[64];
  if (threadIdx.x < 64) yc[threadIdx.x] = ych[blockIdx.y * 64 + threadIdx.x];
  __syncthreads();
  const int p = blockIdx.x * 256 + threadIdx.x;
  const int b = blockIdx.y;
  float s = 0.f, mx = -1e30f;
  for (int c = 0; c < 64; ++c) {
    float v = star0[((size_t)b * 64 + c) * HWN + p] * yc[c];
    s += v;
    mx = fmaxf(mx, v);
  }
  spmean[(size_t)b * HWN + p] = s * (1.f / 64.f);
  spmax[(size_t)b * HWN + p] = mx;
}

// ---------------- K8: 7x7 conv on [mean,max] -> sigmoid ----------------------
__global__ __launch_bounds__(256) void k_spconv(const float* __restrict__ spmean,
    const float* __restrict__ spmax, const float* __restrict__ w,
    float* __restrict__ spat) {
  const int p = blockIdx.x * 256 + threadIdx.x;
  const int b = blockIdx.y;
  const int y = p / WW, x = p - y * WW;
  const float* me = spmean + (size_t)b * HWN;
  const float* mx = spmax + (size_t)b * HWN;
  float acc = 0.f;
#pragma unroll
  for (int dy = 0; dy < 7; ++dy) {
    int yy = y + dy - 3;
    if ((unsigned)yy >= (unsigned)HH) continue;
#pragma unroll
    for (int dx = 0; dx < 7; ++dx) {
      int xx = x + dx - 3;
      if ((unsigned)xx >= (unsigned)WW) continue;
      acc = fmaf(w[dy * 7 + dx], me[yy * WW + xx], acc);
      acc = fmaf(w[49 + dy * 7 + dx], mx[yy * WW + xx], acc);
    }
  }
  spat[(size_t)b * HWN + p] = sigf(acc);
}

// ---------------- K9: MFMA GEMM 128->256 + BN + SiLU + residual --------------
// B built on the fly from star0/hb/ych/spat (fused mkB). grid (50, 2, 16)
__global__ __launch_bounds__(256) void k_expand_mfma(
    const float* __restrict__ star0, const float* __restrict__ hbuf,
    const float* __restrict__ ych, const float* __restrict__ spat,
    const float* __restrict__ blend, const ushortT* __restrict__ Wb,
    const float* __restrict__ bn, const float* __restrict__ xin,
    float* __restrict__ outp) {
  __shared__ ushortT As[128 * 32];
  __shared__ unsigned BsU[128 * 20];
  __shared__ float Ep[4 * 16 * 66];
  __shared__ float Sp[128];
  __shared__ float Yc[64];
  const int t = threadIdx.x;
  const int w = t >> 6, l = t & 63;
  const int p0 = blockIdx.x * 128;
  const int c0 = blockIdx.y * 128;
  const int b = blockIdx.z;
  const int wm = (w >> 1) * 64, wn = (w & 1) * 64;
  const float alpha = sigf(blend[0]);
  const float beta = 1.f - alpha;
  if (t < 128) Sp[t] = alpha * spat[(size_t)b * HWN + p0 + t];
  else if (t < 192) Yc[t - 128] = ych[b * 64 + (t - 128)];
  f32x4 acc[4][4] = {};
  const int srow = l >> 2, scol = (l & 3) * 8;
  for (int k0 = 0; k0 < 128; k0 += 32) {
    __syncthreads();
    gl_lds16(Wb + (size_t)(c0 + (w * 2) * 16 + srow) * 128 + k0 + scol, &As[(w * 2) * 16 * 32]);
    gl_lds16(Wb + (size_t)(c0 + (w * 2 + 1) * 16 + srow) * 128 + k0 + scol, &As[(w * 2 + 1) * 16 * 32]);
    const int ch0 = k0 >> 1;
#pragma unroll
    for (int pass = 0; pass < 8; ++pass) {
      int idx = pass * 256 + t;
      int p_l = idx & 127, chl = idx >> 7;
      int ch = ch0 + chl;
      size_t o = ((size_t)b * 64 + ch) * HWN + p0 + p_l;
      float vs = star0[o] * Yc[ch] * Sp[p_l];   // even k: star branch
      float vh = beta * hbuf[o];                // odd k: hb branch
      BsU[bs_w(p_l, chl)] = (unsigned)f2bf(vs) | ((unsigned)f2bf(vh) << 16);
    }
    __syncthreads();
    const int q = l >> 4, r16 = l & 15;
    short8 a[4], bv[4];
#pragma unroll
    for (int i = 0; i < 4; ++i)
      a[i] = *reinterpret_cast<const short8*>(&As[(wm + i * 16 + r16) * 32 + q * 8]);
#pragma unroll
    for (int j = 0; j < 4; ++j) {
      int row = wn + j * 16 + r16;
      bv[j] = *reinterpret_cast<const short8*>(&BsU[bs_r(row, q)]);
    }
#pragma unroll
    for (int i = 0; i < 4; ++i)
#pragma unroll
      for (int j = 0; j < 4; ++j)
        acc[i][j] = __builtin_amdgcn_mfma_f32_16x16x32_bf16(a[i], bv[j], acc[i][j], 0, 0, 0);
  }
  float* T = Ep + w * (16 * 66);
  const int col = l & 15, rowq = (l >> 4) * 4;
#pragma unroll
  for (int i = 0; i < 4; ++i) {
#pragma unroll
    for (int r = 0; r < 4; ++r)
#pragma unroll
      for (int j = 0; j < 4; ++j)
        T[(rowq + r) * 66 + j * 16 + col] = acc[i][j][r];
#pragma unroll
    for (int pass = 0; pass < 4; ++pass) {
      int row_l = pass * 4 + (l >> 4);
      const float4 v = *reinterpret_cast<const float4*>(&T[row_l * 66 + col * 4]);
      int c = c0 + wm + i * 16 + row_l;
      float s = bn[c] * rsqrtf(bn[768 + c] + 1e-5f);
      float tt = bn[256 + c] - bn[512 + c] * s;
      size_t o = ((size_t)b * 256 + c) * HWN + p0 + wn + col * 4;
      const float4 xr = *reinterpret_cast<const float4*>(xin + o);
      float4 ov;
      ov.x = siluf(v.x * s + tt) + xr.x;
      ov.y = siluf(v.y * s + tt) + xr.y;
      ov.z = siluf(v.z * s + tt) + xr.z;
      ov.w = siluf(v.w * s + tt) + xr.w;
      *reinterpret_cast<float4*>(outp + o) = ov;
    }
  }
}

extern "C" void kernel_launch(void* const* d_in, const int* in_sizes, int n_in,
                              void* d_out, int out_size, void* d_ws, size_t ws_size,
                              hipStream_t stream) {
  const float* x         = (const float*)d_in[0];
  const float* w_reduce  = (const float*)d_in[1];
  const float* bn_reduce = (const float*)d_in[2];
  const float* dcn_off_w = (const float*)d_in[3];
  const float* dcn_off_b = (const float*)d_in[4];
  const float* dcn_dw_w  = (const float*)d_in[5];
  const float* dcn_pw_w  = (const float*)d_in[6];
  const float* bn_dcn    = (const float*)d_in[7];
  const float* w_d2      = (const float*)d_in[8];
  const float* bn_d2     = (const float*)d_in[9];
  const float* w_d3      = (const float*)d_in[10];
  const float* bn_d3     = (const float*)d_in[11];
  const float* w_asym1   = (const float*)d_in[12];
  const float* bn_asym1  = (const float*)d_in[13];
  const float* w_asym2   = (const float*)d_in[14];
  const float* bn_asym2  = (const float*)d_in[15];
  const float* ctx_w     = (const float*)d_in[16];
  const float* bn_star   = (const float*)d_in[17];
  const float* eca_w     = (const float*)d_in[18];
  const float* sp_w      = (const float*)d_in[19];
  const float* blend     = (const float*)d_in[20];
  const float* w_expand  = (const float*)d_in[21];
  const float* bn_expand = (const float*)d_in[22];
  float* out = (float*)d_out;
  float* ws = (float*)d_ws;

  float* slotA = ws;                    // hs
  float* slotB = ws + BIGN;             // hb
  float* slotC = ws + 2 * BIGN;         // dw output
  float* slotD = ws + 3 * BIGN;         // dcn, then star0 (in-place)
  float* sm = ws + 4 * BIGN;
  float* sx     = sm;                   // alias spmean (disjoint lifetime)
  float* sy     = sm + 102400;          // alias spmax
  float* msk    = sm + 204800;          // alias spat
  float* spmean = sx;
  float* spmax  = sy;
  float* spat   = msk;
  float* cmean  = sm + 307200;
  float* ych    = sm + 308224;
  ushortT* Wrb = (ushortT*)(sm + 309248);
  ushortT* Web = Wrb + 32768;

  k_cvtw<<<dim3(256), 256, 0, stream>>>(w_reduce, w_expand, Wrb, Web);
  k_reduce_mfma<<<dim3(50, 1, 16), 256, 0, stream>>>(x, Wrb, bn_reduce, slotA, slotB);
  k_offset<<<dim3(5, 5, 16), 256, 0, stream>>>(slotA, dcn_off_w, dcn_off_b, sx, sy, msk);
  k_gsdw<<<dim3(25, 64, 16), 256, 0, stream>>>(slotA, sx, sy, msk, dcn_dw_w, slotC);
  k_pw<<<dim3(100, 1, 16), 256, 0, stream>>>(slotC, dcn_pw_w, bn_dcn, slotD);
  k_ctxstar<<<dim3(25, 64, 16), 256, 0, stream>>>(slotA, slotD, w_d2, bn_d2,
                                                  w_d3, bn_d3, w_asym1, bn_asym1,
                                                  w_asym2, bn_asym2, ctx_w, bn_star, slotD);
  k_cmean<<<dim3(64, 16), 256, 0, stream>>>(slotD, cmean);
  k_eca<<<dim3(1), 1024, 0, stream>>>(cmean, eca_w, ych);
  k_spstats<<<dim3(25, 16), 256, 0, stream>>>(slotD, ych, spmean, spmax);
  k_spconv<<<dim3(25, 16), 256, 0, stream>>>(spmean, spmax, sp_w, spat);
  k_expand_mfma<<<dim3(50, 2, 16), 256, 0, stream>>>(slotD, slotB, ych, spat, blend,
                                                     Web, bn_expand, x, out);
}

// Round 4
// 478.051 us; speedup vs baseline: 1.3993x; 1.0842x over previous
//
#include <hip/hip_runtime.h>

#define HH 80
#define WW 80
#define HWN 6400
#define BN 16

typedef unsigned short ushortT;
typedef __attribute__((ext_vector_type(8))) short short8;
typedef __attribute__((ext_vector_type(4))) float f32x4;

static constexpr size_t BIGN = (size_t)BN * 64 * HWN;  // 6,553,600 floats

__device__ __forceinline__ float sigf(float v)  { return 1.f / (1.f + __expf(-v)); }
__device__ __forceinline__ float siluf(float v) { return v * sigf(v); }
__device__ __forceinline__ float bnap(float v, const float* __restrict__ bn, int c, int C) {
  float s = bn[c] * rsqrtf(bn[3 * C + c] + 1e-5f);
  return v * s + (bn[C + c] - bn[2 * C + c] * s);
}
__device__ __forceinline__ ushortT f2bf(float f) {  // RNE f32->bf16
  unsigned u = __float_as_uint(f);
  return (ushortT)((u + 0x7FFFu + ((u >> 16) & 1u)) >> 16);
}
__device__ __forceinline__ void gl_lds16(const void* g, void* l) {
  __builtin_amdgcn_global_load_lds(
      (const __attribute__((address_space(1))) unsigned int*)g,
      (__attribute__((address_space(3))) unsigned int*)l, 16, 0, 0);
}
// Bs LDS addressing: [p][k2] uints, row stride 20, 16B-chunk XOR swizzle.
__device__ __forceinline__ int bs_w(int p, int k2) {
  return p * 20 + ((((k2 >> 2) ^ ((p >> 3) & 3)) << 2) | (k2 & 3));
}
__device__ __forceinline__ int bs_r(int p, int q) {
  return p * 20 + (((q ^ ((p >> 3) & 3)) << 2));
}

// ---------------- K0: convert GEMM weights to bf16 ---------------------------
// w_reduce 32768 | w_expand 32768 | dcn_pw_w 4096
__global__ __launch_bounds__(256) void k_cvtw(const float* __restrict__ wr,
    const float* __restrict__ we, const float* __restrict__ wp,
    ushortT* __restrict__ wrb, ushortT* __restrict__ web, ushortT* __restrict__ wpb) {
  int i = blockIdx.x * 256 + threadIdx.x;
  if (i < 32768) wrb[i] = f2bf(wr[i]);
  else if (i < 65536) web[i - 32768] = f2bf(we[i - 32768]);
  else if (i < 69632) wpb[i - 65536] = f2bf(wp[i - 65536]);
}

// ---------------- K1: MFMA GEMM 256->128 + BN + SiLU, fused transpose --------
// grid (50, 1, 16), block 256 (4 waves, each 64c x 64p)
__global__ __launch_bounds__(256) void k_reduce_mfma(
    const float* __restrict__ x, const ushortT* __restrict__ Wb,
    const float* __restrict__ bn, float* __restrict__ hs, float* __restrict__ hb) {
  __shared__ ushortT As[128 * 32];       // [c][k] bf16, stride 32
  __shared__ unsigned BsU[128 * 20];     // [p][k2] swizzled
  __shared__ float Ep[4 * 16 * 68];      // per-wave epilogue transpose
  const int t = threadIdx.x;
  const int w = t >> 6, l = t & 63;
  const int p0 = blockIdx.x * 128;
  const int b = blockIdx.z;
  const int wm = (w >> 1) * 64, wn = (w & 1) * 64;
  f32x4 acc[4][4] = {};
  const float* xb = x + (size_t)b * 256 * HWN;
  const int srow = l >> 2, scol = (l & 3) * 8;
  for (int k0 = 0; k0 < 256; k0 += 32) {
    __syncthreads();
    gl_lds16(Wb + (size_t)((w * 2) * 16 + srow) * 256 + k0 + scol, &As[(w * 2) * 16 * 32]);
    gl_lds16(Wb + (size_t)((w * 2 + 1) * 16 + srow) * 256 + k0 + scol, &As[(w * 2 + 1) * 16 * 32]);
#pragma unroll
    for (int pass = 0; pass < 8; ++pass) {
      int idx = pass * 256 + t;
      int p_l = idx & 127, k2 = idx >> 7;
      int k = k0 + 2 * k2;
      float v0 = xb[(size_t)k * HWN + p0 + p_l];
      float v1 = xb[(size_t)(k + 1) * HWN + p0 + p_l];
      BsU[bs_w(p_l, k2)] = (unsigned)f2bf(v0) | ((unsigned)f2bf(v1) << 16);
    }
    __syncthreads();
    const int q = l >> 4, r16 = l & 15;
    short8 a[4], bv[4];
#pragma unroll
    for (int i = 0; i < 4; ++i)
      a[i] = *reinterpret_cast<const short8*>(&As[(wm + i * 16 + r16) * 32 + q * 8]);
#pragma unroll
    for (int j = 0; j < 4; ++j) {
      int row = wn + j * 16 + r16;
      bv[j] = *reinterpret_cast<const short8*>(&BsU[bs_r(row, q)]);
    }
#pragma unroll
    for (int i = 0; i < 4; ++i)
#pragma unroll
      for (int j = 0; j < 4; ++j)
        acc[i][j] = __builtin_amdgcn_mfma_f32_16x16x32_bf16(a[i], bv[j], acc[i][j], 0, 0, 0);
  }
  float* T = Ep + w * (16 * 68);
  const int col = l & 15, rowq = (l >> 4) * 4;
#pragma unroll
  for (int i = 0; i < 4; ++i) {
#pragma unroll
    for (int r = 0; r < 4; ++r)
#pragma unroll
      for (int j = 0; j < 4; ++j)
        T[(rowq + r) * 68 + j * 16 + col] = acc[i][j][r];
#pragma unroll
    for (int pass = 0; pass < 4; ++pass) {
      int row_l = pass * 4 + (l >> 4);
      const float4 v = *reinterpret_cast<const float4*>(&T[row_l * 68 + col * 4]);
      int c = wm + i * 16 + row_l;
      float s = bn[c] * rsqrtf(bn[384 + c] + 1e-5f);
      float tt = bn[128 + c] - bn[256 + c] * s;
      float4 o;
      o.x = siluf(v.x * s + tt);
      o.y = siluf(v.y * s + tt);
      o.z = siluf(v.z * s + tt);
      o.w = siluf(v.w * s + tt);
      float* dst = (c < 64 ? hs : hb) + ((size_t)b * 64 + (c & 63)) * HWN + p0 + wn + col * 4;
      *reinterpret_cast<float4*>(dst) = o;
    }
  }
}

// ---------------- K2: 3x3 offset conv (64->3), 16 ch per barrier round -------
// grid (25, 16), block 256 (16x16 pixel tile)
__global__ __launch_bounds__(256) void k_offset(const float* __restrict__ hs,
    const float* __restrict__ w, const float* __restrict__ bias,
    float* __restrict__ sx, float* __restrict__ sy, float* __restrict__ msk) {
  __shared__ float ht[16 * 324];
  __shared__ float wt[1728];
  const int t = threadIdx.x;
  const int b = blockIdx.y;
  const int x0 = (blockIdx.x % 5) * 16, y0 = (blockIdx.x / 5) * 16;
  const int lx = t & 15, ly = t >> 4;
  for (int i = t; i < 1728; i += 256) wt[i] = w[i];
  float a0 = 0.f, a1 = 0.f, a2 = 0.f;
  for (int r = 0; r < 4; ++r) {
    __syncthreads();
    for (int i = t; i < 16 * 324; i += 256) {
      int ch = i / 324, pos = i - ch * 324;
      int iy = pos / 18, ix = pos - iy * 18;
      int gy = y0 + iy - 1, gx = x0 + ix - 1;
      ht[i] = ((unsigned)gy < (unsigned)HH && (unsigned)gx < (unsigned)WW)
                  ? hs[((size_t)b * 64 + r * 16 + ch) * HWN + gy * WW + gx] : 0.f;
    }
    __syncthreads();
    for (int ch = 0; ch < 16; ++ch) {
      const float* base = &ht[ch * 324];
      const int c = r * 16 + ch;
#pragma unroll
      for (int dy = 0; dy < 3; ++dy)
#pragma unroll
        for (int dx = 0; dx < 3; ++dx) {
          float v = base[(ly + dy) * 18 + lx + dx];
          a0 = fmaf(wt[c * 9 + dy * 3 + dx], v, a0);
          a1 = fmaf(wt[576 + c * 9 + dy * 3 + dx], v, a1);
          a2 = fmaf(wt[1152 + c * 9 + dy * 3 + dx], v, a2);
        }
    }
  }
  a0 += bias[0];
  a1 += bias[1];
  a2 += bias[2];
  size_t o = (size_t)b * HWN + (y0 + ly) * WW + x0 + lx;
  const float sc = 79.f / 80.f;
  sx[o] = (float)(x0 + lx) + a1 * sc;
  sy[o] = (float)(y0 + ly) + a0 * sc;
  msk[o] = sigf(a2);
}

// ---------------- K3: fused bilinear sample*mask + depthwise 3x3 -------------
__global__ __launch_bounds__(256) void k_gsdw(const float* __restrict__ hs,
    const float* __restrict__ sx, const float* __restrict__ sy,
    const float* __restrict__ msk, const float* __restrict__ wdw,
    float* __restrict__ outp) {
  __shared__ float tile[18 * 18];
  const int t = threadIdx.x;
  const int c = blockIdx.y, b = blockIdx.z;
  const int tx0 = (blockIdx.x % 5) * 16, ty0 = (blockIdx.x / 5) * 16;
  const float* pl = hs + ((size_t)b * 64 + c) * HWN;
  for (int i = t; i < 324; i += 256) {
    int iy = i / 18, ix = i - iy * 18;
    int gy = ty0 + iy - 1, gx = tx0 + ix - 1;
    float v = 0.f;
    if ((unsigned)gy < (unsigned)HH && (unsigned)gx < (unsigned)WW) {
      size_t o = (size_t)b * HWN + gy * WW + gx;
      float gxs = sx[o], gys = sy[o], m = msk[o];
      float x0f = floorf(gxs), y0f = floorf(gys);
      float wx = gxs - x0f, wy = gys - y0f;
      int ix0 = (int)x0f, iy0 = (int)y0f;
      int ix1 = ix0 + 1, iy1 = iy0 + 1;
      float acc = 0.f;
      if ((unsigned)iy0 < (unsigned)HH && (unsigned)ix0 < (unsigned)WW) acc = fmaf(pl[iy0 * WW + ix0], (1.f - wx) * (1.f - wy), acc);
      if ((unsigned)iy0 < (unsigned)HH && (unsigned)ix1 < (unsigned)WW) acc = fmaf(pl[iy0 * WW + ix1], wx * (1.f - wy), acc);
      if ((unsigned)iy1 < (unsigned)HH && (unsigned)ix0 < (unsigned)WW) acc = fmaf(pl[iy1 * WW + ix0], (1.f - wx) * wy, acc);
      if ((unsigned)iy1 < (unsigned)HH && (unsigned)ix1 < (unsigned)WW) acc = fmaf(pl[iy1 * WW + ix1], wx * wy, acc);
      v = acc * m;
    }
    tile[i] = v;
  }
  __syncthreads();
  const int lx = t & 15, ly = t >> 4;
  const float* wc = wdw + c * 9;
  float acc = 0.f;
#pragma unroll
  for (int dy = 0; dy < 3; ++dy)
#pragma unroll
    for (int dx = 0; dx < 3; ++dx)
      acc = fmaf(wc[dy * 3 + dx], tile[(ly + dy) * 18 + lx + dx], acc);
  outp[((size_t)b * 64 + c) * HWN + (ty0 + ly) * WW + tx0 + lx] = acc;
}

// ---------------- K4: MFMA 1x1 conv 64->64 + BN + SiLU -----------------------
// tile 64c x 128p, K=64 in 2 chunks. grid (50, 16), block 256
__global__ __launch_bounds__(256) void k_pw_mfma(const float* __restrict__ in,
    const ushortT* __restrict__ Wpb, const float* __restrict__ bn,
    float* __restrict__ outp) {
  __shared__ ushortT As[2][64 * 32];
  __shared__ unsigned BsU[128 * 20];
  __shared__ float Ep[4 * 16 * 36];
  const int t = threadIdx.x;
  const int w = t >> 6, l = t & 63;
  const int p0 = blockIdx.x * 128;
  const int b = blockIdx.y;
  const int wn = w * 32;
  f32x4 acc[4][2] = {};
  const int srow = l >> 2, scol = (l & 3) * 8;
  gl_lds16(Wpb + (size_t)(w * 16 + srow) * 64 + scol,      &As[0][w * 16 * 32]);
  gl_lds16(Wpb + (size_t)(w * 16 + srow) * 64 + 32 + scol, &As[1][w * 16 * 32]);
  for (int kc = 0; kc < 2; ++kc) {
    __syncthreads();
    const int ch0 = kc * 32;
#pragma unroll
    for (int pass = 0; pass < 8; ++pass) {
      int idx = pass * 256 + t;
      int p_l = idx & 127, k2 = idx >> 7;
      int k = ch0 + 2 * k2;
      float v0 = in[((size_t)b * 64 + k) * HWN + p0 + p_l];
      float v1 = in[((size_t)b * 64 + k + 1) * HWN + p0 + p_l];
      BsU[bs_w(p_l, k2)] = (unsigned)f2bf(v0) | ((unsigned)f2bf(v1) << 16);
    }
    __syncthreads();
    const int q = l >> 4, r16 = l & 15;
    short8 a[4], bv[2];
#pragma unroll
    for (int i = 0; i < 4; ++i)
      a[i] = *reinterpret_cast<const short8*>(&As[kc][(i * 16 + r16) * 32 + q * 8]);
#pragma unroll
    for (int j = 0; j < 2; ++j)
      bv[j] = *reinterpret_cast<const short8*>(&BsU[bs_r(wn + j * 16 + r16, q)]);
#pragma unroll
    for (int i = 0; i < 4; ++i)
#pragma unroll
      for (int j = 0; j < 2; ++j)
        acc[i][j] = __builtin_amdgcn_mfma_f32_16x16x32_bf16(a[i], bv[j], acc[i][j], 0, 0, 0);
  }
  float* T = Ep + w * (16 * 36);
  const int col = l & 15, rowq = (l >> 4) * 4;
#pragma unroll
  for (int i = 0; i < 4; ++i) {
#pragma unroll
    for (int r = 0; r < 4; ++r)
#pragma unroll
      for (int j = 0; j < 2; ++j)
        T[(rowq + r) * 36 + j * 16 + col] = acc[i][j][r];
#pragma unroll
    for (int pass = 0; pass < 2; ++pass) {
      int flat = pass * 64 + l;
      int row_l = flat >> 3, c4 = flat & 7;
      const float4 v = *reinterpret_cast<const float4*>(&T[row_l * 36 + c4 * 4]);
      int c = i * 16 + row_l;
      float s = bn[c] * rsqrtf(bn[192 + c] + 1e-5f);
      float tt = bn[64 + c] - bn[128 + c] * s;
      float4 o;
      o.x = siluf(v.x * s + tt);
      o.y = siluf(v.y * s + tt);
      o.z = siluf(v.z * s + tt);
      o.w = siluf(v.w * s + tt);
      *reinterpret_cast<float4*>(outp + ((size_t)b * 64 + c) * HWN + p0 + wn + c4 * 4) = o;
    }
  }
}

// ---------------- K5: fused a1 + d2 + d3 + asym -> ctx; star0 = BN(dcn*ctx) --
__global__ __launch_bounds__(256) void k_ctxstar(const float* __restrict__ hs,
    const float* __restrict__ dcn,
    const float* __restrict__ wd2, const float* __restrict__ bnd2,
    const float* __restrict__ wd3, const float* __restrict__ bnd3,
    const float* __restrict__ wa1, const float* __restrict__ bna1,
    const float* __restrict__ wa2, const float* __restrict__ bna2,
    const float* __restrict__ cw, const float* __restrict__ bnstar,
    float* __restrict__ star0) {
  __shared__ float ht[22 * 23];
  __shared__ float at[22 * 17];
  const int t = threadIdx.x;
  const int c = blockIdx.y, b = blockIdx.z;
  const int tx0 = (blockIdx.x % 5) * 16, ty0 = (blockIdx.x / 5) * 16;
  const float* pl = hs + ((size_t)b * 64 + c) * HWN;
  for (int i = t; i < 484; i += 256) {
    int iy = i / 22, ix = i - iy * 22;
    int gy = ty0 + iy - 3, gx = tx0 + ix - 3;
    ht[iy * 23 + ix] = ((unsigned)gy < (unsigned)HH && (unsigned)gx < (unsigned)WW)
                           ? pl[gy * WW + gx] : 0.f;
  }
  __syncthreads();
  for (int i = t; i < 352; i += 256) {
    int iy = i >> 4, ix = i & 15;
    int gy = ty0 + iy - 3;
    float v = 0.f;
    if ((unsigned)gy < (unsigned)HH) {
      float s = 0.f;
#pragma unroll
      for (int k = 0; k < 7; ++k) s = fmaf(wa1[c * 7 + k], ht[iy * 23 + ix + k], s);
      v = siluf(bnap(s, bna1, c, 64));
    }
    at[iy * 17 + ix] = v;
  }
  __syncthreads();
  const int lx = t & 15, ly = t >> 4;
  float d2 = 0.f, d3 = 0.f;
#pragma unroll
  for (int dy = 0; dy < 3; ++dy)
#pragma unroll
    for (int dx = 0; dx < 3; ++dx) {
      float w2 = wd2[c * 9 + dy * 3 + dx], w3 = wd3[c * 9 + dy * 3 + dx];
      d2 = fmaf(w2, ht[(ly + 3 + 2 * (dy - 1)) * 23 + lx + 3 + 2 * (dx - 1)], d2);
      d3 = fmaf(w3, ht[(ly + 3 + 3 * (dy - 1)) * 23 + lx + 3 + 3 * (dx - 1)], d3);
    }
  float as = 0.f;
#pragma unroll
  for (int k = 0; k < 7; ++k) as = fmaf(wa2[c * 7 + k], at[(ly + k) * 17 + lx], as);
  d2 = siluf(bnap(d2, bnd2, c, 64));
  d3 = siluf(bnap(d3, bnd3, c, 64));
  as = siluf(bnap(as, bna2, c, 64));
  float e0 = __expf(cw[0]), e1 = __expf(cw[1]), e2 = __expf(cw[2]);
  float inv = 1.f / (e0 + e1 + e2);
  float ctx = (e0 * d2 + e1 * d3 + e2 * as) * inv;
  size_t o = ((size_t)b * 64 + c) * HWN + (ty0 + ly) * WW + tx0 + lx;
  star0[o] = bnap(dcn[o] * ctx, bnstar, c, 64);
}

// ---------------- K6: per-(b,c) spatial mean of star0 ------------------------
__global__ __launch_bounds__(256) void k_cmean(const float* __restrict__ star0,
    float* __restrict__ mean) {
  const int c = blockIdx.x, b = blockIdx.y;
  const float* pl = star0 + ((size_t)b * 64 + c) * HWN;
  float s = 0.f;
  for (int i = threadIdx.x; i < HWN; i += 256) s += pl[i];
  __shared__ float red[256];
  red[threadIdx.x] = s;
  __syncthreads();
  for (int st = 128; st > 0; st >>= 1) {
    if (threadIdx.x < st) red[threadIdx.x] += red[threadIdx.x + st];
    __syncthreads();
  }
  if (threadIdx.x == 0) mean[b * 64 + c] = red[0] * (1.f / HWN);
}

// ---------------- K6b: ECA + sigmoid -----------------------------------------
__global__ __launch_bounds__(1024) void k_eca(const float* __restrict__ mean,
    const float* __restrict__ ew, float* __restrict__ ych) {
  const int t = threadIdx.x;
  const int c = t & 63;
  const int base = t - c;
  float acc = 0.f;
#pragma unroll
  for (int k = 0; k < 5; ++k) {
    int cc = c + k - 2;
    if ((unsigned)cc < 64u) acc = fmaf(ew[k], mean[base + cc], acc);
  }
  ych[t] = sigf(acc);
}

// ---------------- K7: channel mean/max of star0*ych, 4-wave split ------------
// grid (100, 16), block 256: 64 px per block, 4 channel-quarters
__global__ __launch_bounds__(256) void k_spstats(const float* __restrict__ star0,
    const float* __restrict__ ych, float* __restrict__ spmean, float* __restrict__ spmax) {
  __shared__ float yc[64];
  __shared__ float rs[4][64], rm[4][64];
  const int t = threadIdx.x;
  const int b = blockIdx.y;
  const int p0 = blockIdx.x * 64;
  if (t < 64) yc[t] = ych[b * 64 + t];
  __syncthreads();
  const int tq = t >> 6, pix = t & 63;
  float s = 0.f, mx = -1e30f;
  for (int cc = 0; cc < 16; ++cc) {
    int c = tq * 16 + cc;
    float v = star0[((size_t)b * 64 + c) * HWN + p0 + pix] * yc[c];
    s += v;
    mx = fmaxf(mx, v);
  }
  rs[tq][pix] = s;
  rm[tq][pix] = mx;
  __syncthreads();
  if (t < 64) {
    float ss = rs[0][t] + rs[1][t] + rs[2][t] + rs[3][t];
    float mm = fmaxf(fmaxf(rm[0][t], rm[1][t]), fmaxf(rm[2][t], rm[3][t]));
    spmean[(size_t)b * HWN + p0 + t] = ss * (1.f / 64.f);
    spmax[(size_t)b * HWN + p0 + t] = mm;
  }
}

// ---------------- K8: 7x7 conv on [mean,max] -> sigmoid ----------------------
__global__ __launch_bounds__(256) void k_spconv(const float* __restrict__ spmean,
    const float* __restrict__ spmax, const float* __restrict__ w,
    float* __restrict__ spat) {
  const int p = blockIdx.x * 256 + threadIdx.x;
  const int b = blockIdx.y;
  const int y = p / WW, x = p - y * WW;
  const float* me = spmean + (size_t)b * HWN;
  const float* mx = spmax + (size_t)b * HWN;
  float acc = 0.f;
#pragma unroll
  for (int dy = 0; dy < 7; ++dy) {
    int yy = y + dy - 3;
    if ((unsigned)yy >= (unsigned)HH) continue;
#pragma unroll
    for (int dx = 0; dx < 7; ++dx) {
      int xx = x + dx - 3;
      if ((unsigned)xx >= (unsigned)WW) continue;
      acc = fmaf(w[dy * 7 + dx], me[yy * WW + xx], acc);
      acc = fmaf(w[49 + dy * 7 + dx], mx[yy * WW + xx], acc);
    }
  }
  spat[(size_t)b * HWN + p] = sigf(acc);
}

// ---------------- K9: MFMA GEMM 128->256 + BN + SiLU + residual --------------
// grid (50, 2, 16), block 256
__global__ __launch_bounds__(256) void k_expand_mfma(
    const float* __restrict__ star0, const float* __restrict__ hbuf,
    const float* __restrict__ ych, const float* __restrict__ spat,
    const float* __restrict__ blend, const ushortT* __restrict__ Wb,
    const float* __restrict__ bn, const float* __restrict__ xin,
    float* __restrict__ outp) {
  __shared__ ushortT As[128 * 32];
  __shared__ unsigned BsU[128 * 20];
  __shared__ float Ep[4 * 16 * 68];
  __shared__ float Sp[128];
  __shared__ float Yc[64];
  const int t = threadIdx.x;
  const int w = t >> 6, l = t & 63;
  const int p0 = blockIdx.x * 128;
  const int c0 = blockIdx.y * 128;
  const int b = blockIdx.z;
  const int wm = (w >> 1) * 64, wn = (w & 1) * 64;
  const float alpha = sigf(blend[0]);
  const float beta = 1.f - alpha;
  if (t < 128) Sp[t] = alpha * spat[(size_t)b * HWN + p0 + t];
  else if (t < 192) Yc[t - 128] = ych[b * 64 + (t - 128)];
  f32x4 acc[4][4] = {};
  const int srow = l >> 2, scol = (l & 3) * 8;
  for (int k0 = 0; k0 < 128; k0 += 32) {
    __syncthreads();
    gl_lds16(Wb + (size_t)(c0 + (w * 2) * 16 + srow) * 128 + k0 + scol, &As[(w * 2) * 16 * 32]);
    gl_lds16(Wb + (size_t)(c0 + (w * 2 + 1) * 16 + srow) * 128 + k0 + scol, &As[(w * 2 + 1) * 16 * 32]);
    const int ch0 = k0 >> 1;
#pragma unroll
    for (int pass = 0; pass < 8; ++pass) {
      int idx = pass * 256 + t;
      int p_l = idx & 127, chl = idx >> 7;
      int ch = ch0 + chl;
      size_t o = ((size_t)b * 64 + ch) * HWN + p0 + p_l;
      float vs = star0[o] * Yc[ch] * Sp[p_l];
      float vh = beta * hbuf[o];
      BsU[bs_w(p_l, chl)] = (unsigned)f2bf(vs) | ((unsigned)f2bf(vh) << 16);
    }
    __syncthreads();
    const int q = l >> 4, r16 = l & 15;
    short8 a[4], bv[4];
#pragma unroll
    for (int i = 0; i < 4; ++i)
      a[i] = *reinterpret_cast<const short8*>(&As[(wm + i * 16 + r16) * 32 + q * 8]);
#pragma unroll
    for (int j = 0; j < 4; ++j) {
      int row = wn + j * 16 + r16;
      bv[j] = *reinterpret_cast<const short8*>(&BsU[bs_r(row, q)]);
    }
#pragma unroll
    for (int i = 0; i < 4; ++i)
#pragma unroll
      for (int j = 0; j < 4; ++j)
        acc[i][j] = __builtin_amdgcn_mfma_f32_16x16x32_bf16(a[i], bv[j], acc[i][j], 0, 0, 0);
  }
  float* T = Ep + w * (16 * 68);
  const int col = l & 15, rowq = (l >> 4) * 4;
#pragma unroll
  for (int i = 0; i < 4; ++i) {
#pragma unroll
    for (int r = 0; r < 4; ++r)
#pragma unroll
      for (int j = 0; j < 4; ++j)
        T[(rowq + r) * 68 + j * 16 + col] = acc[i][j][r];
#pragma unroll
    for (int pass = 0; pass < 4; ++pass) {
      int row_l = pass * 4 + (l >> 4);
      const float4 v = *reinterpret_cast<const float4*>(&T[row_l * 68 + col * 4]);
      int c = c0 + wm + i * 16 + row_l;
      float s = bn[c] * rsqrtf(bn[768 + c] + 1e-5f);
      float tt = bn[256 + c] - bn[512 + c] * s;
      size_t o = ((size_t)b * 256 + c) * HWN + p0 + wn + col * 4;
      const float4 xr = *reinterpret_cast<const float4*>(xin + o);
      float4 ov;
      ov.x = siluf(v.x * s + tt) + xr.x;
      ov.y = siluf(v.y * s + tt) + xr.y;
      ov.z = siluf(v.z * s + tt) + xr.z;
      ov.w = siluf(v.w * s + tt) + xr.w;
      *reinterpret_cast<float4*>(outp + o) = ov;
    }
  }
}

extern "C" void kernel_launch(void* const* d_in, const int* in_sizes, int n_in,
                              void* d_out, int out_size, void* d_ws, size_t ws_size,
                              hipStream_t stream) {
  const float* x         = (const float*)d_in[0];
  const float* w_reduce  = (const float*)d_in[1];
  const float* bn_reduce = (const float*)d_in[2];
  const float* dcn_off_w = (const float*)d_in[3];
  const float* dcn_off_b = (const float*)d_in[4];
  const float* dcn_dw_w  = (const float*)d_in[5];
  const float* dcn_pw_w  = (const float*)d_in[6];
  const float* bn_dcn    = (const float*)d_in[7];
  const float* w_d2      = (const float*)d_in[8];
  const float* bn_d2     = (const float*)d_in[9];
  const float* w_d3      = (const float*)d_in[10];
  const float* bn_d3     = (const float*)d_in[11];
  const float* w_asym1   = (const float*)d_in[12];
  const float* bn_asym1  = (const float*)d_in[13];
  const float* w_asym2   = (const float*)d_in[14];
  const float* bn_asym2  = (const float*)d_in[15];
  const float* ctx_w     = (const float*)d_in[16];
  const float* bn_star   = (const float*)d_in[17];
  const float* eca_w     = (const float*)d_in[18];
  const float* sp_w      = (const float*)d_in[19];
  const float* blend     = (const float*)d_in[20];
  const float* w_expand  = (const float*)d_in[21];
  const float* bn_expand = (const float*)d_in[22];
  float* out = (float*)d_out;
  float* ws = (float*)d_ws;

  float* slotA = ws;                    // hs
  float* slotB = ws + BIGN;             // hb
  float* slotC = ws + 2 * BIGN;         // dw output
  float* slotD = ws + 3 * BIGN;         // dcn, then star0 (in-place)
  float* sm = ws + 4 * BIGN;
  float* sx     = sm;                   // alias spmean (disjoint lifetime)
  float* sy     = sm + 102400;          // alias spmax
  float* msk    = sm + 204800;          // alias spat
  float* spmean = sx;
  float* spmax  = sy;
  float* spat   = msk;
  float* cmean  = sm + 307200;
  float* ych    = sm + 308224;
  ushortT* Wrb = (ushortT*)(sm + 309248);
  ushortT* Web = Wrb + 32768;
  ushortT* Wpb = Web + 32768;

  k_cvtw<<<dim3(272), 256, 0, stream>>>(w_reduce, w_expand, dcn_pw_w, Wrb, Web, Wpb);
  k_reduce_mfma<<<dim3(50, 1, 16), 256, 0, stream>>>(x, Wrb, bn_reduce, slotA, slotB);
  k_offset<<<dim3(25, 16), 256, 0, stream>>>(slotA, dcn_off_w, dcn_off_b, sx, sy, msk);
  k_gsdw<<<dim3(25, 64, 16), 256, 0, stream>>>(slotA, sx, sy, msk, dcn_dw_w, slotC);
  k_pw_mfma<<<dim3(50, 16), 256, 0, stream>>>(slotC, Wpb, bn_dcn, slotD);
  k_ctxstar<<<dim3(25, 64, 16), 256, 0, stream>>>(slotA, slotD, w_d2, bn_d2,
                                                  w_d3, bn_d3, w_asym1, bn_asym1,
                                                  w_asym2, bn_asym2, ctx_w, bn_star, slotD);
  k_cmean<<<dim3(64, 16), 256, 0, stream>>>(slotD, cmean);
  k_eca<<<dim3(1), 1024, 0, stream>>>(cmean, eca_w, ych);
  k_spstats<<<dim3(100, 16), 256, 0, stream>>>(slotD, ych, spmean, spmax);
  k_spconv<<<dim3(25, 16), 256, 0, stream>>>(spmean, spmax, sp_w, spat);
  k_expand_mfma<<<dim3(50, 2, 16), 256, 0, stream>>>(slotD, slotB, ych, spat, blend,
                                                     Web, bn_expand, x, out);
}